// Round 14
// baseline (293.273 us; speedup 1.0000x reference)
//
#include <hip/hip_runtime.h>
#include <hip/hip_fp16.h>
#include <hip/hip_fp8.h>
#include <cstdint>
#include <cstddef>

#define N_NODES  100000
#define N_EDGES  3200000
#define N_GRAPHS 64

#define BQBITS   9
#define BQ       512                      // nodes per bucket
#define NBUCK    196                      // ceil(100000/512)
#define TILE     4096                     // edges per pass-1 block
#define NBLK     782                      // ceil(3200000/4096)
#define POOL_SLICES 8
#define PADB     4608                     // per-bucket padding slack

// ---------------- CSR build: bucketed 2-pass counting sort ----------------

__global__ void kp1_hist(const int* __restrict__ dst, int* __restrict__ gh, int ne) {
    __shared__ int h[NBUCK];
    for (int i = threadIdx.x; i < NBUCK; i += 256) h[i] = 0;
    __syncthreads();
    int base = blockIdx.x * TILE;
    for (int i = threadIdx.x; i < TILE; i += 256) {
        int e = base + i;
        if (e < ne) atomicAdd(&h[dst[e] >> BQBITS], 1);
    }
    __syncthreads();
    for (int i = threadIdx.x; i < NBUCK; i += 256) gh[i * NBLK + blockIdx.x] = h[i];
}

__global__ void kp1_scanA(int* __restrict__ gh, int* __restrict__ btotal) {
    int q = blockIdx.x;
    __shared__ int ts[256];
    int v[4];
    int tsum = 0;
#pragma unroll
    for (int u = 0; u < 4; ++u) {
        int idx = threadIdx.x * 4 + u;
        v[u] = (idx < NBLK) ? gh[q * NBLK + idx] : 0;
        tsum += v[u];
    }
    ts[threadIdx.x] = tsum;
    __syncthreads();
    for (int off = 1; off < 256; off <<= 1) {
        int t = (threadIdx.x >= off) ? ts[threadIdx.x - off] : 0;
        __syncthreads();
        ts[threadIdx.x] += t;
        __syncthreads();
    }
    int run = ts[threadIdx.x] - tsum;
#pragma unroll
    for (int u = 0; u < 4; ++u) {
        int idx = threadIdx.x * 4 + u;
        if (idx < NBLK) gh[q * NBLK + idx] = run;
        run += v[u];
    }
    if (threadIdx.x == 255) btotal[q] = ts[255];
}

__global__ void kp1_scanB(const int* __restrict__ btotal, int* __restrict__ bstart) {
    __shared__ int s[256];
    int v = (threadIdx.x < NBUCK) ? btotal[threadIdx.x] : 0;
    s[threadIdx.x] = v;
    __syncthreads();
    for (int off = 1; off < 256; off <<= 1) {
        int t = (threadIdx.x >= off) ? s[threadIdx.x - off] : 0;
        __syncthreads();
        s[threadIdx.x] += t;
        __syncthreads();
    }
    if (threadIdx.x < NBUCK) bstart[threadIdx.x] = s[threadIdx.x] - v;
    if (threadIdx.x == 0) bstart[NBUCK] = N_EDGES;
}

// block-local counting sort -> bucket-runs in LDS -> coalesced run copy to tmp
__global__ __launch_bounds__(256) void kp1_scatter(
        const int* __restrict__ src, const int* __restrict__ dst,
        const int* __restrict__ gh, const int* __restrict__ bstart,
        unsigned* __restrict__ tmp, int ne) {
    __shared__ unsigned sed[TILE];        // 16 KB
    __shared__ int lcnt[NBUCK];
    __shared__ int lofs[NBUCK + 1];
    __shared__ int fill[NBUCK];
    __shared__ int delta[NBUCK];
    __shared__ int ts[256];
    for (int i = threadIdx.x; i < NBUCK; i += 256) { lcnt[i] = 0; fill[i] = 0; }
    __syncthreads();
    int base = blockIdx.x * TILE;
    int nh = ne - base; if (nh > TILE) nh = TILE;
    int myq[16]; unsigned myw[16];
#pragma unroll
    for (int u = 0; u < 16; ++u) {
        int i = u * 256 + threadIdx.x;
        myq[u] = -1;
        if (i < nh) {
            int d = dst[base + i], s = src[base + i];
            int q = d >> BQBITS;
            myq[u] = q;
            myw[u] = ((unsigned)(d & (BQ - 1)) << 17) | (unsigned)s;
            atomicAdd(&lcnt[q], 1);
        }
    }
    __syncthreads();
    int v = (threadIdx.x < NBUCK) ? lcnt[threadIdx.x] : 0;
    ts[threadIdx.x] = v;
    __syncthreads();
    for (int off = 1; off < 256; off <<= 1) {
        int t = (threadIdx.x >= off) ? ts[threadIdx.x - off] : 0;
        __syncthreads();
        ts[threadIdx.x] += t;
        __syncthreads();
    }
    if (threadIdx.x < NBUCK) {
        int start = ts[threadIdx.x] - v;
        lofs[threadIdx.x] = start;
        delta[threadIdx.x] = bstart[threadIdx.x] + gh[threadIdx.x * NBLK + blockIdx.x] - start;
    }
    if (threadIdx.x == NBUCK - 1) lofs[NBUCK] = ts[threadIdx.x];
    __syncthreads();
#pragma unroll
    for (int u = 0; u < 16; ++u) {
        if (myq[u] >= 0) {
            int r = atomicAdd(&fill[myq[u]], 1);
            sed[lofs[myq[u]] + r] = myw[u];
        }
    }
    __syncthreads();
    for (int p = threadIdx.x; p < nh; p += 256) {
        int lo = 0, hi = NBUCK;                 // run q = largest with lofs[q] <= p
        while (hi - lo > 1) { int mid = (lo + hi) >> 1; if (lofs[mid] <= p) lo = mid; else hi = mid; }
        tmp[p + delta[lo]] = sed[p];
    }
}

// one block per bucket: node counting sort -> rs/deg + 8-padded perm segments
__global__ void kp2(const unsigned* __restrict__ tmp, const int* __restrict__ bstart,
                    int* __restrict__ rs, int* __restrict__ deg, int* __restrict__ perm) {
    int q = blockIdx.x;
    int beg = bstart[q], end = bstart[q + 1];
    int m = end - beg;
    int pbase = ((beg + 7) & ~7) + q * PADB;
    __shared__ int cnt[BQ];
    __shared__ int lofs[BQ];
    __shared__ int fill[BQ];
    if (threadIdx.x < BQ) { cnt[threadIdx.x] = 0; fill[threadIdx.x] = 0; }
    __syncthreads();
    for (int p = threadIdx.x; p < m; p += 1024)
        atomicAdd(&cnt[tmp[beg + p] >> 17], 1);
    __syncthreads();
    int pc = 0;
    if (threadIdx.x < BQ) { pc = (cnt[threadIdx.x] + 7) & ~7; lofs[threadIdx.x] = pc; }
    __syncthreads();
    for (int off = 1; off < BQ; off <<= 1) {
        int t = 0;
        if (threadIdx.x < BQ && threadIdx.x >= off) t = lofs[threadIdx.x - off];
        __syncthreads();
        if (threadIdx.x < BQ) lofs[threadIdx.x] += t;   // inclusive over padded counts
        __syncthreads();
    }
    if (threadIdx.x < BQ) {
        int node = q * BQ + threadIdx.x;
        if (node < N_NODES) {
            int st = lofs[threadIdx.x] - pc;
            rs[node] = pbase + st;
            deg[node] = cnt[threadIdx.x];
            for (int i = cnt[threadIdx.x]; i < pc; ++i)
                perm[pbase + st + i] = N_NODES;          // pad -> zero row
        }
    }
    __syncthreads();
    for (int p = threadIdx.x; p < m; p += 1024) {
        unsigned w = tmp[beg + p];
        int dl = w >> 17;
        int s = w & 0x1FFFF;
        int r = atomicAdd(&fill[dl], 1);
        int st = lofs[dl] - ((cnt[dl] + 7) & ~7);
        perm[pbase + st + r] = s;
    }
}

// ---------------- fp8 helpers ----------------

__device__ __forceinline__ void accq(uint2 v, float* a) {
    unsigned x = v.x, y = v.y;
#pragma unroll
    for (int j = 0; j < 4; ++j) {
        __hip_fp8_e4m3 q0, q1;
        q0.__x = (__hip_fp8_storage_t)((x >> (8 * j)) & 0xFF);
        q1.__x = (__hip_fp8_storage_t)((y >> (8 * j)) & 0xFF);
        a[j]     += (float)q0;
        a[4 + j] += (float)q1;
    }
}

__device__ __forceinline__ uint2 pack8_fp8(const float* a) {
    unsigned lo = 0, hi = 0;
#pragma unroll
    for (int j = 0; j < 4; ++j) {
        lo |= (unsigned)__hip_fp8_e4m3(a[j]).__x << (8 * j);
        hi |= (unsigned)__hip_fp8_e4m3(a[4 + j]).__x << (8 * j);
    }
    uint2 o; o.x = lo; o.y = hi; return o;
}

// ---------------- zero pads + gsum ----------------

__global__ void k_zero(uint2* __restrict__ y1qz, uint2* __restrict__ hqz,
                       unsigned char* __restrict__ y3qz, float* __restrict__ gsum) {
    int t = threadIdx.x;
    if (t < 2) { y1qz[t] = make_uint2(0, 0); hqz[t] = make_uint2(0, 0); }
    if (t < 24) y3qz[t] = 0;
    for (int i = t; i < N_GRAPHS * 32; i += 256) gsum[i] = 0.f;
}

// ---------------- transforms ----------------

// y1q(fp8,[N][16]) = x @ W1l ; s1(f32) = x @ W1r + b1      (64 -> 16)
__global__ void k_t1(const float* __restrict__ x, const float* __restrict__ W1l,
                     const float* __restrict__ W1r, const float* __restrict__ b1,
                     uint2* __restrict__ y1q, float* __restrict__ s1, int n) {
    __shared__ float wl[64 * 16], wr[64 * 16], bb[16];
    for (int i = threadIdx.x; i < 64 * 16; i += blockDim.x) { wl[i] = W1l[i]; wr[i] = W1r[i]; }
    if (threadIdx.x < 16) bb[threadIdx.x] = b1[threadIdx.x];
    __syncthreads();
    int node = blockIdx.x * blockDim.x + threadIdx.x;
    if (node >= n) return;
    const float4* xr = reinterpret_cast<const float4*>(x + (size_t)node * 64);
    float accl[16], accr[16];
#pragma unroll
    for (int j = 0; j < 16; ++j) { accl[j] = 0.f; accr[j] = 0.f; }
#pragma unroll
    for (int q = 0; q < 16; ++q) {
        float4 v = xr[q];
        float xs[4] = {v.x, v.y, v.z, v.w};
#pragma unroll
        for (int u = 0; u < 4; ++u) {
            int k = q * 4 + u;
            float xv = xs[u];
#pragma unroll
            for (int j = 0; j < 16; ++j) {
                accl[j] += xv * wl[k * 16 + j];
                accr[j] += xv * wr[k * 16 + j];
            }
        }
    }
    y1q[(size_t)node * 2 + 0] = pack8_fp8(accl);
    y1q[(size_t)node * 2 + 1] = pack8_fp8(accl + 8);
    float4* s4 = reinterpret_cast<float4*>(s1 + (size_t)node * 16);
#pragma unroll
    for (int q = 0; q < 4; ++q)
        s4[q] = make_float4(accr[q*4+0] + bb[q*4+0], accr[q*4+1] + bb[q*4+1],
                            accr[q*4+2] + bb[q*4+2], accr[q*4+3] + bb[q*4+3]);
}

// h2(f32) = mean2 @ W2l + h(half) @ W2r + b2      (16 -> 32)
__global__ void k_t2(const float* __restrict__ mean2, const __half* __restrict__ h,
                     const float* __restrict__ W2l, const float* __restrict__ W2r,
                     const float* __restrict__ b2, float* __restrict__ h2, int n) {
    __shared__ float wl[16 * 32], wr[16 * 32], bb[32];
    for (int i = threadIdx.x; i < 16 * 32; i += blockDim.x) { wl[i] = W2l[i]; wr[i] = W2r[i]; }
    if (threadIdx.x < 32) bb[threadIdx.x] = b2[threadIdx.x];
    __syncthreads();
    int node = blockIdx.x * blockDim.x + threadIdx.x;
    if (node >= n) return;
    float m[16], hh[16];
    const float4* m4 = reinterpret_cast<const float4*>(mean2 + (size_t)node * 16);
#pragma unroll
    for (int q = 0; q < 4; ++q) {
        float4 a = m4[q];
        m[q*4+0]=a.x; m[q*4+1]=a.y; m[q*4+2]=a.z; m[q*4+3]=a.w;
    }
    alignas(16) __half hv[16];
    const uint4* hp = reinterpret_cast<const uint4*>(h + (size_t)node * 16);
    uint4* hvp = reinterpret_cast<uint4*>(hv);
    hvp[0] = hp[0]; hvp[1] = hp[1];
#pragma unroll
    for (int k = 0; k < 16; ++k) hh[k] = __half2float(hv[k]);
    float acc[32];
#pragma unroll
    for (int j = 0; j < 32; ++j) acc[j] = bb[j];
#pragma unroll
    for (int k = 0; k < 16; ++k) {
#pragma unroll
        for (int j = 0; j < 32; ++j)
            acc[j] += m[k] * wl[k * 32 + j] + hh[k] * wr[k * 32 + j];
    }
    float4* o4 = reinterpret_cast<float4*>(h2 + (size_t)node * 32);
#pragma unroll
    for (int q = 0; q < 8; ++q)
        o4[q] = make_float4(acc[q*4+0], acc[q*4+1], acc[q*4+2], acc[q*4+3]);
}

// z = relu(h2); y3q(fp8, stride 24B) = z @ W3l ; s3(f32, stride 24) = z @ W3r + b3
__global__ void k_t3(const float* __restrict__ h2, const float* __restrict__ W3l,
                     const float* __restrict__ W3r, const float* __restrict__ b3,
                     unsigned char* __restrict__ y3q, float* __restrict__ s3, int n) {
    __shared__ float wl[32 * 21], wr[32 * 21], bb[21];
    for (int i = threadIdx.x; i < 32 * 21; i += blockDim.x) { wl[i] = W3l[i]; wr[i] = W3r[i]; }
    if (threadIdx.x < 21) bb[threadIdx.x] = b3[threadIdx.x];
    __syncthreads();
    int node = blockIdx.x * blockDim.x + threadIdx.x;
    if (node >= n) return;
    float z[32];
    const float4* h4 = reinterpret_cast<const float4*>(h2 + (size_t)node * 32);
#pragma unroll
    for (int q = 0; q < 8; ++q) {
        float4 v = h4[q];
        z[q*4+0] = fmaxf(v.x, 0.f); z[q*4+1] = fmaxf(v.y, 0.f);
        z[q*4+2] = fmaxf(v.z, 0.f); z[q*4+3] = fmaxf(v.w, 0.f);
    }
    float a[24], c[21];
#pragma unroll
    for (int j = 0; j < 21; ++j) { a[j] = 0.f; c[j] = bb[j]; }
    a[21] = 0.f; a[22] = 0.f; a[23] = 0.f;
#pragma unroll
    for (int k = 0; k < 32; ++k) {
#pragma unroll
        for (int j = 0; j < 21; ++j) {
            a[j] += z[k] * wl[k * 21 + j];
            c[j] += z[k] * wr[k * 21 + j];
        }
    }
    uint2* yp = reinterpret_cast<uint2*>(y3q + (size_t)node * 24);
    yp[0] = pack8_fp8(a);
    yp[1] = pack8_fp8(a + 8);
    yp[2] = pack8_fp8(a + 16);
    float* so = s3 + (size_t)node * 24;
#pragma unroll
    for (int j = 0; j < 21; ++j) so[j] = c[j];
    so[21] = 0.f; so[22] = 0.f; so[23] = 0.f;
}

// ---- aggregation: fp8 tables, padded segments, int4 perm loads ----

// layer 1: 2 lanes/node, gathers y1q (uint2 = 8 fp8), +self +relu -> h fp16 + hq fp8
__global__ void k_agg_l1(const uint2* __restrict__ yq, const int* __restrict__ rs,
                         const int* __restrict__ deg, const int* __restrict__ perm,
                         const float* __restrict__ s1, __half* __restrict__ h,
                         uint2* __restrict__ hq, int n_nodes) {
    int t = blockIdx.x * blockDim.x + threadIdx.x;
    int node = t >> 1;
    int f = t & 1;
    if (node >= n_nodes) return;
    int beg = rs[node];
    int d = deg[node];
    int pend = beg + ((d + 7) & ~7);
    float a[8];
#pragma unroll
    for (int j = 0; j < 8; ++j) a[j] = 0.f;
    for (int e = beg; e < pend; e += 8) {
        const int4* pp = reinterpret_cast<const int4*>(perm + e);
        int4 p0 = pp[0];
        int4 p1 = pp[1];
        uint2 v0 = yq[(size_t)p0.x * 2 + f];
        uint2 v1 = yq[(size_t)p0.y * 2 + f];
        uint2 v2 = yq[(size_t)p0.z * 2 + f];
        uint2 v3 = yq[(size_t)p0.w * 2 + f];
        uint2 v4 = yq[(size_t)p1.x * 2 + f];
        uint2 v5 = yq[(size_t)p1.y * 2 + f];
        uint2 v6 = yq[(size_t)p1.z * 2 + f];
        uint2 v7 = yq[(size_t)p1.w * 2 + f];
        accq(v0, a); accq(v1, a); accq(v2, a); accq(v3, a);
        accq(v4, a); accq(v5, a); accq(v6, a); accq(v7, a);
    }
    float inv = 1.0f / fmaxf((float)d, 1.0f);
    const float4* sp = reinterpret_cast<const float4*>(s1 + (size_t)node * 16 + f * 8);
    float4 s0 = sp[0], s1v = sp[1];
    a[0] = fmaxf(a[0] * inv + s0.x, 0.f);
    a[1] = fmaxf(a[1] * inv + s0.y, 0.f);
    a[2] = fmaxf(a[2] * inv + s0.z, 0.f);
    a[3] = fmaxf(a[3] * inv + s0.w, 0.f);
    a[4] = fmaxf(a[4] * inv + s1v.x, 0.f);
    a[5] = fmaxf(a[5] * inv + s1v.y, 0.f);
    a[6] = fmaxf(a[6] * inv + s1v.z, 0.f);
    a[7] = fmaxf(a[7] * inv + s1v.w, 0.f);
    // fp16 copy for k_t2 self-path
    __half2 p0h = __floats2half2_rn(a[0], a[1]);
    __half2 p1h = __floats2half2_rn(a[2], a[3]);
    __half2 p2h = __floats2half2_rn(a[4], a[5]);
    __half2 p3h = __floats2half2_rn(a[6], a[7]);
    uint4 o;
    o.x = *reinterpret_cast<unsigned*>(&p0h);
    o.y = *reinterpret_cast<unsigned*>(&p1h);
    o.z = *reinterpret_cast<unsigned*>(&p2h);
    o.w = *reinterpret_cast<unsigned*>(&p3h);
    reinterpret_cast<uint4*>(h)[(size_t)node * 2 + f] = o;
    // fp8 gather table for layer 2
    hq[(size_t)node * 2 + f] = pack8_fp8(a);
}

// layer 2: 2 lanes/node, gathers hq -> mean2 f32
__global__ void k_agg_l2(const uint2* __restrict__ hq, const int* __restrict__ rs,
                         const int* __restrict__ deg, const int* __restrict__ perm,
                         float* __restrict__ mean2, int n_nodes) {
    int t = blockIdx.x * blockDim.x + threadIdx.x;
    int node = t >> 1;
    int f = t & 1;
    if (node >= n_nodes) return;
    int beg = rs[node];
    int d = deg[node];
    int pend = beg + ((d + 7) & ~7);
    float a[8];
#pragma unroll
    for (int j = 0; j < 8; ++j) a[j] = 0.f;
    for (int e = beg; e < pend; e += 8) {
        const int4* pp = reinterpret_cast<const int4*>(perm + e);
        int4 p0 = pp[0];
        int4 p1 = pp[1];
        uint2 v0 = hq[(size_t)p0.x * 2 + f];
        uint2 v1 = hq[(size_t)p0.y * 2 + f];
        uint2 v2 = hq[(size_t)p0.z * 2 + f];
        uint2 v3 = hq[(size_t)p0.w * 2 + f];
        uint2 v4 = hq[(size_t)p1.x * 2 + f];
        uint2 v5 = hq[(size_t)p1.y * 2 + f];
        uint2 v6 = hq[(size_t)p1.z * 2 + f];
        uint2 v7 = hq[(size_t)p1.w * 2 + f];
        accq(v0, a); accq(v1, a); accq(v2, a); accq(v3, a);
        accq(v4, a); accq(v5, a); accq(v6, a); accq(v7, a);
    }
    float inv = 1.0f / fmaxf((float)d, 1.0f);
    float4* op = reinterpret_cast<float4*>(mean2 + (size_t)node * 16 + f * 8);
    op[0] = make_float4(a[0] * inv, a[1] * inv, a[2] * inv, a[3] * inv);
    op[1] = make_float4(a[4] * inv, a[5] * inv, a[6] * inv, a[7] * inv);
}

// layer 3: 3 lanes/node over stride-24B fp8 table; self stride 24; out stride 21
__global__ void k_agg_l3(const unsigned char* __restrict__ y3q, const int* __restrict__ rs,
                         const int* __restrict__ deg, const int* __restrict__ perm,
                         const float* __restrict__ self24, float* __restrict__ outp,
                         int n_nodes) {
    int t = blockIdx.x * blockDim.x + threadIdx.x;
    int node = t / 3;
    int f = t - node * 3;
    if (node >= n_nodes) return;
    const uint2* yq = reinterpret_cast<const uint2*>(y3q);
    int beg = rs[node];
    int d = deg[node];
    int pend = beg + ((d + 7) & ~7);
    float a[8];
#pragma unroll
    for (int j = 0; j < 8; ++j) a[j] = 0.f;
    for (int e = beg; e < pend; e += 8) {
        const int4* pp = reinterpret_cast<const int4*>(perm + e);
        int4 p0 = pp[0];
        int4 p1 = pp[1];
        uint2 v0 = yq[(size_t)p0.x * 3 + f];
        uint2 v1 = yq[(size_t)p0.y * 3 + f];
        uint2 v2 = yq[(size_t)p0.z * 3 + f];
        uint2 v3 = yq[(size_t)p0.w * 3 + f];
        uint2 v4 = yq[(size_t)p1.x * 3 + f];
        uint2 v5 = yq[(size_t)p1.y * 3 + f];
        uint2 v6 = yq[(size_t)p1.z * 3 + f];
        uint2 v7 = yq[(size_t)p1.w * 3 + f];
        accq(v0, a); accq(v1, a); accq(v2, a); accq(v3, a);
        accq(v4, a); accq(v5, a); accq(v6, a); accq(v7, a);
    }
    float inv = 1.0f / fmaxf((float)d, 1.0f);
    int c0 = f * 8;
    const float4* sp = reinterpret_cast<const float4*>(self24 + (size_t)node * 24 + c0);
    float4 s0 = sp[0], s1 = sp[1];
    float r[8];
    r[0] = a[0] * inv + s0.x; r[1] = a[1] * inv + s0.y;
    r[2] = a[2] * inv + s0.z; r[3] = a[3] * inv + s0.w;
    r[4] = a[4] * inv + s1.x; r[5] = a[5] * inv + s1.y;
    r[6] = a[6] * inv + s1.z; r[7] = a[7] * inv + s1.w;
    float* op = outp + (size_t)node * 21;
    int nlim = 21 - c0;                 // 21, 13, or 5
#pragma unroll
    for (int j = 0; j < 8; ++j)
        if (j < nlim) op[c0 + j] = r[j];
}

// ---------------- pooling + classifier ----------------

__device__ __forceinline__ int lowerb(const int* a, int n, int key) {
    int lo = 0, hi = n;
    while (lo < hi) { int mid = (lo + hi) >> 1; if (a[mid] < key) lo = mid + 1; else hi = mid; }
    return lo;
}

__global__ void k_pool(const float* __restrict__ h2, const int* __restrict__ batch,
                       float* __restrict__ gsum, float* __restrict__ gcnt, int n) {
    int g = blockIdx.x / POOL_SLICES;
    int slice = blockIdx.x - g * POOL_SLICES;
    __shared__ int sbeg, send;
    if (threadIdx.x == 0) { sbeg = lowerb(batch, n, g); send = lowerb(batch, n, g + 1); }
    __syncthreads();
    int beg = sbeg, end = send;
    int f = threadIdx.x & 31;
    int r = threadIdx.x >> 5;   // 8 row-groups
    float acc = 0.f;
    for (int i = beg + slice * 8 + r; i < end; i += POOL_SLICES * 8)
        acc += h2[(size_t)i * 32 + f];
    __shared__ float red[256];
    red[threadIdx.x] = acc;
    __syncthreads();
    if (r == 0) {
        float s = 0.f;
#pragma unroll
        for (int q = 0; q < 8; ++q) s += red[q * 32 + f];
        atomicAdd(&gsum[g * 32 + f], s);
    }
    if (slice == 0 && threadIdx.x == 0) gcnt[g] = (float)(end - beg);
}

__global__ void k_cls(const float* __restrict__ gsum, const float* __restrict__ gcnt,
                      const float* __restrict__ Wc, const float* __restrict__ bc,
                      float* __restrict__ outp) {
    int t = threadIdx.x;
    if (t >= N_GRAPHS * 10) return;
    int g = t / 10, c = t - g * 10;
    float cv = fmaxf(gcnt[g], 1.f);
    float acc = bc[c];
#pragma unroll
    for (int k = 0; k < 32; ++k) acc += (gsum[g * 32 + k] / cv) * Wc[k * 10 + c];
    outp[g * 10 + c] = acc;
}

// ---------------- launch ----------------

extern "C" void kernel_launch(void* const* d_in, const int* in_sizes, int n_in,
                              void* d_out, int out_size, void* d_ws, size_t ws_size,
                              hipStream_t stream) {
    const float* x    = (const float*)d_in[0];
    const int*   ei   = (const int*)d_in[1];
    const int*   batch= (const int*)d_in[2];
    const float* W1l  = (const float*)d_in[3];
    const float* b1   = (const float*)d_in[4];
    const float* W1r  = (const float*)d_in[5];
    const float* W2l  = (const float*)d_in[6];
    const float* b2   = (const float*)d_in[7];
    const float* W2r  = (const float*)d_in[8];
    const float* W3l  = (const float*)d_in[9];
    const float* b3   = (const float*)d_in[10];
    const float* W3r  = (const float*)d_in[11];
    const float* Wc   = (const float*)d_in[12];
    const float* bc   = (const float*)d_in[13];
    float* out = (float*)d_out;

    char* ws = (char*)d_ws;
    size_t off = 0;
    auto alloc = [&](size_t bytes) { size_t o = off; off += (bytes + 255) & ~(size_t)255; return o; };

    int*    rs    = (int*)(ws + alloc((size_t)N_NODES * 4));
    int*    deg   = (int*)(ws + alloc((size_t)N_NODES * 4));
    int*    perm  = (int*)(ws + alloc((size_t)(N_EDGES + (size_t)NBUCK * PADB + 64) * 4));
    int*    gh    = (int*)(ws + alloc((size_t)NBUCK * NBLK * 4));
    int*    btotal= (int*)(ws + alloc(256 * 4));
    int*    bstart= (int*)(ws + alloc(260 * 4));
    uint2*  y1q   = (uint2*)(ws + alloc((size_t)(N_NODES + 1) * 16));      // fp8 [N+1][16]
    float*  s1    = (float*)(ws + alloc((size_t)N_NODES * 16 * 4));
    __half* h     = (__half*)(ws + alloc((size_t)N_NODES * 16 * 2));       // fp16 self copy
    uint2*  hq    = (uint2*)(ws + alloc((size_t)(N_NODES + 1) * 16));      // fp8 [N+1][16]
    float*  mean2 = (float*)(ws + alloc((size_t)N_NODES * 16 * 4));
    float*  h2    = (float*)(ws + alloc((size_t)N_NODES * 32 * 4));
    unsigned char* y3q = (unsigned char*)(ws + alloc((size_t)(N_NODES + 1) * 24)); // fp8 stride24
    float*  s3    = (float*)(ws + alloc((size_t)N_NODES * 24 * 4));
    float*  gsum  = (float*)(ws + alloc((size_t)N_GRAPHS * 32 * 4));
    float*  gcnt  = (float*)(ws + alloc((size_t)N_GRAPHS * 4));

    // tmp (12.8 MB) aliases h2 (12.8 MB): tmp dead before k_t2 writes h2
    unsigned* tmp = (unsigned*)h2;

    const int* src = ei;
    const int* dst = ei + N_EDGES;

    int nb  = (N_NODES + 255) / 256;                 // 391
    int g2  = (N_NODES * 2 + 255) / 256;             // 782
    int g3  = (N_NODES * 3 + 255) / 256;             // 1172

    // zero pad rows (gather row N_NODES) + gsum
    k_zero<<<1, 256, 0, stream>>>(y1q + (size_t)N_NODES * 2, hq + (size_t)N_NODES * 2,
                                  y3q + (size_t)N_NODES * 24, gsum);

    // CSR build (bucketed 2-pass counting sort, 8-padded per-node segments)
    kp1_hist   <<<NBLK, 256, 0, stream>>>(dst, gh, N_EDGES);
    kp1_scanA  <<<NBUCK, 256, 0, stream>>>(gh, btotal);
    kp1_scanB  <<<1, 256, 0, stream>>>(btotal, bstart);
    kp1_scatter<<<NBLK, 256, 0, stream>>>(src, dst, gh, bstart, tmp, N_EDGES);
    kp2        <<<NBUCK, 1024, 0, stream>>>(tmp, bstart, rs, deg, perm);

    // layer 1: transform-first (64->16); fp8-table aggregate (+self +relu) -> h fp16 + hq fp8
    k_t1<<<nb, 256, 0, stream>>>(x, W1l, W1r, b1, y1q, s1, N_NODES);
    k_agg_l1<<<g2, 256, 0, stream>>>(y1q, rs, deg, perm, s1, h, hq, N_NODES);

    // layer 2: fp8-table aggregate-first -> mean2 (f32), then 16->32
    k_agg_l2<<<g2, 256, 0, stream>>>(hq, rs, deg, perm, mean2, N_NODES);
    k_t2<<<nb, 256, 0, stream>>>(mean2, h, W2l, W2r, b2, h2, N_NODES);

    // layer 3: transform-first on relu(h2) (32->21); fp8-table aggregate, +self
    k_t3<<<nb, 256, 0, stream>>>(h2, W3l, W3r, b3, y3q, s3, N_NODES);
    k_agg_l3<<<g3, 256, 0, stream>>>(y3q, rs, deg, perm, s3, out + N_GRAPHS * 10, N_NODES);

    // pooling over h2 (pre-relu) + classifier
    k_pool<<<N_GRAPHS * POOL_SLICES, 256, 0, stream>>>(h2, batch, gsum, gcnt, N_NODES);
    k_cls<<<1, 640, 0, stream>>>(gsum, gcnt, Wc, bc, out);
}

// Round 15
// 214.906 us; speedup vs baseline: 1.3647x; 1.3647x over previous
//
#include <hip/hip_runtime.h>
#include <hip/hip_fp16.h>
#include <cstdint>
#include <cstddef>

#define N_NODES  100000
#define N_EDGES  3200000
#define N_GRAPHS 64

#define BQBITS   9
#define BQ       512                      // nodes per bucket
#define NBUCK    196                      // ceil(100000/512)
#define TILE     4096                     // edges per pass-1 block
#define NBLK     782                      // ceil(3200000/4096)
#define POOL_SLICES 8
#define PADB     4608                     // per-bucket padding slack

typedef float vf2 __attribute__((ext_vector_type(2)));

// ---------------- CSR build: bucketed 2-pass counting sort ----------------

__global__ void kp1_hist(const int* __restrict__ dst, int* __restrict__ gh, int ne) {
    __shared__ int h[NBUCK];
    for (int i = threadIdx.x; i < NBUCK; i += 256) h[i] = 0;
    __syncthreads();
    int base = blockIdx.x * TILE;
    for (int i = threadIdx.x; i < TILE; i += 256) {
        int e = base + i;
        if (e < ne) atomicAdd(&h[dst[e] >> BQBITS], 1);
    }
    __syncthreads();
    for (int i = threadIdx.x; i < NBUCK; i += 256) gh[i * NBLK + blockIdx.x] = h[i];
}

__global__ void kp1_scanA(int* __restrict__ gh, int* __restrict__ btotal) {
    int q = blockIdx.x;
    __shared__ int ts[256];
    int v[4];
    int tsum = 0;
#pragma unroll
    for (int u = 0; u < 4; ++u) {
        int idx = threadIdx.x * 4 + u;
        v[u] = (idx < NBLK) ? gh[q * NBLK + idx] : 0;
        tsum += v[u];
    }
    ts[threadIdx.x] = tsum;
    __syncthreads();
    for (int off = 1; off < 256; off <<= 1) {
        int t = (threadIdx.x >= off) ? ts[threadIdx.x - off] : 0;
        __syncthreads();
        ts[threadIdx.x] += t;
        __syncthreads();
    }
    int run = ts[threadIdx.x] - tsum;
#pragma unroll
    for (int u = 0; u < 4; ++u) {
        int idx = threadIdx.x * 4 + u;
        if (idx < NBLK) gh[q * NBLK + idx] = run;
        run += v[u];
    }
    if (threadIdx.x == 255) btotal[q] = ts[255];
}

__global__ void kp1_scanB(const int* __restrict__ btotal, int* __restrict__ bstart) {
    __shared__ int s[256];
    int v = (threadIdx.x < NBUCK) ? btotal[threadIdx.x] : 0;
    s[threadIdx.x] = v;
    __syncthreads();
    for (int off = 1; off < 256; off <<= 1) {
        int t = (threadIdx.x >= off) ? s[threadIdx.x - off] : 0;
        __syncthreads();
        s[threadIdx.x] += t;
        __syncthreads();
    }
    if (threadIdx.x < NBUCK) bstart[threadIdx.x] = s[threadIdx.x] - v;
    if (threadIdx.x == 0) bstart[NBUCK] = N_EDGES;
}

// block-local counting sort -> bucket-runs in LDS -> coalesced run copy to tmp
__global__ __launch_bounds__(256) void kp1_scatter(
        const int* __restrict__ src, const int* __restrict__ dst,
        const int* __restrict__ gh, const int* __restrict__ bstart,
        unsigned* __restrict__ tmp, int ne) {
    __shared__ unsigned sed[TILE];        // 16 KB
    __shared__ int lcnt[NBUCK];
    __shared__ int lofs[NBUCK + 1];
    __shared__ int fill[NBUCK];
    __shared__ int delta[NBUCK];
    __shared__ int ts[256];
    for (int i = threadIdx.x; i < NBUCK; i += 256) { lcnt[i] = 0; fill[i] = 0; }
    __syncthreads();
    int base = blockIdx.x * TILE;
    int nh = ne - base; if (nh > TILE) nh = TILE;
    int myq[16]; unsigned myw[16];
#pragma unroll
    for (int u = 0; u < 16; ++u) {
        int i = u * 256 + threadIdx.x;
        myq[u] = -1;
        if (i < nh) {
            int d = dst[base + i], s = src[base + i];
            int q = d >> BQBITS;
            myq[u] = q;
            myw[u] = ((unsigned)(d & (BQ - 1)) << 17) | (unsigned)s;
            atomicAdd(&lcnt[q], 1);
        }
    }
    __syncthreads();
    int v = (threadIdx.x < NBUCK) ? lcnt[threadIdx.x] : 0;
    ts[threadIdx.x] = v;
    __syncthreads();
    for (int off = 1; off < 256; off <<= 1) {
        int t = (threadIdx.x >= off) ? ts[threadIdx.x - off] : 0;
        __syncthreads();
        ts[threadIdx.x] += t;
        __syncthreads();
    }
    if (threadIdx.x < NBUCK) {
        int start = ts[threadIdx.x] - v;
        lofs[threadIdx.x] = start;
        delta[threadIdx.x] = bstart[threadIdx.x] + gh[threadIdx.x * NBLK + blockIdx.x] - start;
    }
    if (threadIdx.x == NBUCK - 1) lofs[NBUCK] = ts[threadIdx.x];
    __syncthreads();
#pragma unroll
    for (int u = 0; u < 16; ++u) {
        if (myq[u] >= 0) {
            int r = atomicAdd(&fill[myq[u]], 1);
            sed[lofs[myq[u]] + r] = myw[u];
        }
    }
    __syncthreads();
    for (int p = threadIdx.x; p < nh; p += 256) {
        int lo = 0, hi = NBUCK;                 // run q = largest with lofs[q] <= p
        while (hi - lo > 1) { int mid = (lo + hi) >> 1; if (lofs[mid] <= p) lo = mid; else hi = mid; }
        tmp[p + delta[lo]] = sed[p];
    }
}

// one block per bucket: node counting sort -> rs/deg + 8-padded perm segments
__global__ void kp2(const unsigned* __restrict__ tmp, const int* __restrict__ bstart,
                    int* __restrict__ rs, int* __restrict__ deg, int* __restrict__ perm) {
    int q = blockIdx.x;
    int beg = bstart[q], end = bstart[q + 1];
    int m = end - beg;
    int pbase = ((beg + 7) & ~7) + q * PADB;
    __shared__ int cnt[BQ];
    __shared__ int lofs[BQ];
    __shared__ int fill[BQ];
    if (threadIdx.x < BQ) { cnt[threadIdx.x] = 0; fill[threadIdx.x] = 0; }
    __syncthreads();
    for (int p = threadIdx.x; p < m; p += 1024)
        atomicAdd(&cnt[tmp[beg + p] >> 17], 1);
    __syncthreads();
    int pc = 0;
    if (threadIdx.x < BQ) { pc = (cnt[threadIdx.x] + 7) & ~7; lofs[threadIdx.x] = pc; }
    __syncthreads();
    for (int off = 1; off < BQ; off <<= 1) {
        int t = 0;
        if (threadIdx.x < BQ && threadIdx.x >= off) t = lofs[threadIdx.x - off];
        __syncthreads();
        if (threadIdx.x < BQ) lofs[threadIdx.x] += t;   // inclusive over padded counts
        __syncthreads();
    }
    if (threadIdx.x < BQ) {
        int node = q * BQ + threadIdx.x;
        if (node < N_NODES) {
            int st = lofs[threadIdx.x] - pc;
            rs[node] = pbase + st;
            deg[node] = cnt[threadIdx.x];
            for (int i = cnt[threadIdx.x]; i < pc; ++i)
                perm[pbase + st + i] = N_NODES;          // pad -> zero row
        }
    }
    __syncthreads();
    for (int p = threadIdx.x; p < m; p += 1024) {
        unsigned w = tmp[beg + p];
        int dl = w >> 17;
        int s = w & 0x1FFFF;
        int r = atomicAdd(&fill[dl], 1);
        int st = lofs[dl] - ((cnt[dl] + 7) & ~7);
        perm[pbase + st + r] = s;
    }
}

// ---------------- fp8 helpers (HW packed converts) ----------------

__device__ __forceinline__ void accq(uint2 v, float* a) {
    vf2 f0 = __builtin_amdgcn_cvt_pk_f32_fp8((int)v.x, false);
    vf2 f1 = __builtin_amdgcn_cvt_pk_f32_fp8((int)v.x, true);
    vf2 f2 = __builtin_amdgcn_cvt_pk_f32_fp8((int)v.y, false);
    vf2 f3 = __builtin_amdgcn_cvt_pk_f32_fp8((int)v.y, true);
    a[0] += f0.x; a[1] += f0.y; a[2] += f1.x; a[3] += f1.y;
    a[4] += f2.x; a[5] += f2.y; a[6] += f3.x; a[7] += f3.y;
}

__device__ __forceinline__ uint2 pack8_fp8(const float* a) {
    int lo = __builtin_amdgcn_cvt_pk_fp8_f32(a[0], a[1], 0, false);
    lo     = __builtin_amdgcn_cvt_pk_fp8_f32(a[2], a[3], lo, true);
    int hi = __builtin_amdgcn_cvt_pk_fp8_f32(a[4], a[5], 0, false);
    hi     = __builtin_amdgcn_cvt_pk_fp8_f32(a[6], a[7], hi, true);
    uint2 o; o.x = (unsigned)lo; o.y = (unsigned)hi; return o;
}

// ---------------- zero pads + gsum ----------------

__global__ void k_zero(uint2* __restrict__ y1qz, uint2* __restrict__ hqz,
                       unsigned char* __restrict__ y3qz, float* __restrict__ gsum) {
    int t = threadIdx.x;
    if (t < 2) { y1qz[t] = make_uint2(0, 0); hqz[t] = make_uint2(0, 0); }
    if (t < 24) y3qz[t] = 0;
    for (int i = t; i < N_GRAPHS * 32; i += 256) gsum[i] = 0.f;
}

// ---------------- transforms ----------------

// y1q(fp8,[N][16]) = x @ W1l ; s1(f32) = x @ W1r + b1      (64 -> 16)
__global__ void k_t1(const float* __restrict__ x, const float* __restrict__ W1l,
                     const float* __restrict__ W1r, const float* __restrict__ b1,
                     uint2* __restrict__ y1q, float* __restrict__ s1, int n) {
    __shared__ float wl[64 * 16], wr[64 * 16], bb[16];
    for (int i = threadIdx.x; i < 64 * 16; i += blockDim.x) { wl[i] = W1l[i]; wr[i] = W1r[i]; }
    if (threadIdx.x < 16) bb[threadIdx.x] = b1[threadIdx.x];
    __syncthreads();
    int node = blockIdx.x * blockDim.x + threadIdx.x;
    if (node >= n) return;
    const float4* xr = reinterpret_cast<const float4*>(x + (size_t)node * 64);
    float accl[16], accr[16];
#pragma unroll
    for (int j = 0; j < 16; ++j) { accl[j] = 0.f; accr[j] = 0.f; }
#pragma unroll
    for (int q = 0; q < 16; ++q) {
        float4 v = xr[q];
        float xs[4] = {v.x, v.y, v.z, v.w};
#pragma unroll
        for (int u = 0; u < 4; ++u) {
            int k = q * 4 + u;
            float xv = xs[u];
#pragma unroll
            for (int j = 0; j < 16; ++j) {
                accl[j] += xv * wl[k * 16 + j];
                accr[j] += xv * wr[k * 16 + j];
            }
        }
    }
    y1q[(size_t)node * 2 + 0] = pack8_fp8(accl);
    y1q[(size_t)node * 2 + 1] = pack8_fp8(accl + 8);
    float4* s4 = reinterpret_cast<float4*>(s1 + (size_t)node * 16);
#pragma unroll
    for (int q = 0; q < 4; ++q)
        s4[q] = make_float4(accr[q*4+0] + bb[q*4+0], accr[q*4+1] + bb[q*4+1],
                            accr[q*4+2] + bb[q*4+2], accr[q*4+3] + bb[q*4+3]);
}

// h2(f32) = mean2 @ W2l + h(half) @ W2r + b2      (16 -> 32)
__global__ void k_t2(const float* __restrict__ mean2, const __half* __restrict__ h,
                     const float* __restrict__ W2l, const float* __restrict__ W2r,
                     const float* __restrict__ b2, float* __restrict__ h2, int n) {
    __shared__ float wl[16 * 32], wr[16 * 32], bb[32];
    for (int i = threadIdx.x; i < 16 * 32; i += blockDim.x) { wl[i] = W2l[i]; wr[i] = W2r[i]; }
    if (threadIdx.x < 32) bb[threadIdx.x] = b2[threadIdx.x];
    __syncthreads();
    int node = blockIdx.x * blockDim.x + threadIdx.x;
    if (node >= n) return;
    float m[16], hh[16];
    const float4* m4 = reinterpret_cast<const float4*>(mean2 + (size_t)node * 16);
#pragma unroll
    for (int q = 0; q < 4; ++q) {
        float4 a = m4[q];
        m[q*4+0]=a.x; m[q*4+1]=a.y; m[q*4+2]=a.z; m[q*4+3]=a.w;
    }
    alignas(16) __half hv[16];
    const uint4* hp = reinterpret_cast<const uint4*>(h + (size_t)node * 16);
    uint4* hvp = reinterpret_cast<uint4*>(hv);
    hvp[0] = hp[0]; hvp[1] = hp[1];
#pragma unroll
    for (int k = 0; k < 16; ++k) hh[k] = __half2float(hv[k]);
    float acc[32];
#pragma unroll
    for (int j = 0; j < 32; ++j) acc[j] = bb[j];
#pragma unroll
    for (int k = 0; k < 16; ++k) {
#pragma unroll
        for (int j = 0; j < 32; ++j)
            acc[j] += m[k] * wl[k * 32 + j] + hh[k] * wr[k * 32 + j];
    }
    float4* o4 = reinterpret_cast<float4*>(h2 + (size_t)node * 32);
#pragma unroll
    for (int q = 0; q < 8; ++q)
        o4[q] = make_float4(acc[q*4+0], acc[q*4+1], acc[q*4+2], acc[q*4+3]);
}

// z = relu(h2); y3q(fp8, stride 24B) = z @ W3l ; s3(f32, stride 24) = z @ W3r + b3
__global__ void k_t3(const float* __restrict__ h2, const float* __restrict__ W3l,
                     const float* __restrict__ W3r, const float* __restrict__ b3,
                     unsigned char* __restrict__ y3q, float* __restrict__ s3, int n) {
    __shared__ float wl[32 * 21], wr[32 * 21], bb[21];
    for (int i = threadIdx.x; i < 32 * 21; i += blockDim.x) { wl[i] = W3l[i]; wr[i] = W3r[i]; }
    if (threadIdx.x < 21) bb[threadIdx.x] = b3[threadIdx.x];
    __syncthreads();
    int node = blockIdx.x * blockDim.x + threadIdx.x;
    if (node >= n) return;
    float z[32];
    const float4* h4 = reinterpret_cast<const float4*>(h2 + (size_t)node * 32);
#pragma unroll
    for (int q = 0; q < 8; ++q) {
        float4 v = h4[q];
        z[q*4+0] = fmaxf(v.x, 0.f); z[q*4+1] = fmaxf(v.y, 0.f);
        z[q*4+2] = fmaxf(v.z, 0.f); z[q*4+3] = fmaxf(v.w, 0.f);
    }
    float a[24], c[21];
#pragma unroll
    for (int j = 0; j < 21; ++j) { a[j] = 0.f; c[j] = bb[j]; }
    a[21] = 0.f; a[22] = 0.f; a[23] = 0.f;
#pragma unroll
    for (int k = 0; k < 32; ++k) {
#pragma unroll
        for (int j = 0; j < 21; ++j) {
            a[j] += z[k] * wl[k * 21 + j];
            c[j] += z[k] * wr[k * 21 + j];
        }
    }
    uint2* yp = reinterpret_cast<uint2*>(y3q + (size_t)node * 24);
    yp[0] = pack8_fp8(a);
    yp[1] = pack8_fp8(a + 8);
    yp[2] = pack8_fp8(a + 16);
    float* so = s3 + (size_t)node * 24;
#pragma unroll
    for (int j = 0; j < 21; ++j) so[j] = c[j];
    so[21] = 0.f; so[22] = 0.f; so[23] = 0.f;
}

// ---- aggregation: fp8 tables, padded segments, int4 perm loads ----

// layer 1: 2 lanes/node, gathers y1q (uint2 = 8 fp8), +self +relu -> h fp16 + hq fp8
__global__ void k_agg_l1(const uint2* __restrict__ yq, const int* __restrict__ rs,
                         const int* __restrict__ deg, const int* __restrict__ perm,
                         const float* __restrict__ s1, __half* __restrict__ h,
                         uint2* __restrict__ hq, int n_nodes) {
    int t = blockIdx.x * blockDim.x + threadIdx.x;
    int node = t >> 1;
    int f = t & 1;
    if (node >= n_nodes) return;
    int beg = rs[node];
    int d = deg[node];
    int pend = beg + ((d + 7) & ~7);
    float a[8];
#pragma unroll
    for (int j = 0; j < 8; ++j) a[j] = 0.f;
    for (int e = beg; e < pend; e += 8) {
        const int4* pp = reinterpret_cast<const int4*>(perm + e);
        int4 p0 = pp[0];
        int4 p1 = pp[1];
        uint2 v0 = yq[(size_t)p0.x * 2 + f];
        uint2 v1 = yq[(size_t)p0.y * 2 + f];
        uint2 v2 = yq[(size_t)p0.z * 2 + f];
        uint2 v3 = yq[(size_t)p0.w * 2 + f];
        uint2 v4 = yq[(size_t)p1.x * 2 + f];
        uint2 v5 = yq[(size_t)p1.y * 2 + f];
        uint2 v6 = yq[(size_t)p1.z * 2 + f];
        uint2 v7 = yq[(size_t)p1.w * 2 + f];
        accq(v0, a); accq(v1, a); accq(v2, a); accq(v3, a);
        accq(v4, a); accq(v5, a); accq(v6, a); accq(v7, a);
    }
    float inv = 1.0f / fmaxf((float)d, 1.0f);
    const float4* sp = reinterpret_cast<const float4*>(s1 + (size_t)node * 16 + f * 8);
    float4 s0 = sp[0], s1v = sp[1];
    a[0] = fmaxf(a[0] * inv + s0.x, 0.f);
    a[1] = fmaxf(a[1] * inv + s0.y, 0.f);
    a[2] = fmaxf(a[2] * inv + s0.z, 0.f);
    a[3] = fmaxf(a[3] * inv + s0.w, 0.f);
    a[4] = fmaxf(a[4] * inv + s1v.x, 0.f);
    a[5] = fmaxf(a[5] * inv + s1v.y, 0.f);
    a[6] = fmaxf(a[6] * inv + s1v.z, 0.f);
    a[7] = fmaxf(a[7] * inv + s1v.w, 0.f);
    // fp16 copy for k_t2 self-path
    __half2 p0h = __floats2half2_rn(a[0], a[1]);
    __half2 p1h = __floats2half2_rn(a[2], a[3]);
    __half2 p2h = __floats2half2_rn(a[4], a[5]);
    __half2 p3h = __floats2half2_rn(a[6], a[7]);
    uint4 o;
    o.x = *reinterpret_cast<unsigned*>(&p0h);
    o.y = *reinterpret_cast<unsigned*>(&p1h);
    o.z = *reinterpret_cast<unsigned*>(&p2h);
    o.w = *reinterpret_cast<unsigned*>(&p3h);
    reinterpret_cast<uint4*>(h)[(size_t)node * 2 + f] = o;
    // fp8 gather table for layer 2
    hq[(size_t)node * 2 + f] = pack8_fp8(a);
}

// layer 2: 2 lanes/node, gathers hq -> mean2 f32
__global__ void k_agg_l2(const uint2* __restrict__ hq, const int* __restrict__ rs,
                         const int* __restrict__ deg, const int* __restrict__ perm,
                         float* __restrict__ mean2, int n_nodes) {
    int t = blockIdx.x * blockDim.x + threadIdx.x;
    int node = t >> 1;
    int f = t & 1;
    if (node >= n_nodes) return;
    int beg = rs[node];
    int d = deg[node];
    int pend = beg + ((d + 7) & ~7);
    float a[8];
#pragma unroll
    for (int j = 0; j < 8; ++j) a[j] = 0.f;
    for (int e = beg; e < pend; e += 8) {
        const int4* pp = reinterpret_cast<const int4*>(perm + e);
        int4 p0 = pp[0];
        int4 p1 = pp[1];
        uint2 v0 = hq[(size_t)p0.x * 2 + f];
        uint2 v1 = hq[(size_t)p0.y * 2 + f];
        uint2 v2 = hq[(size_t)p0.z * 2 + f];
        uint2 v3 = hq[(size_t)p0.w * 2 + f];
        uint2 v4 = hq[(size_t)p1.x * 2 + f];
        uint2 v5 = hq[(size_t)p1.y * 2 + f];
        uint2 v6 = hq[(size_t)p1.z * 2 + f];
        uint2 v7 = hq[(size_t)p1.w * 2 + f];
        accq(v0, a); accq(v1, a); accq(v2, a); accq(v3, a);
        accq(v4, a); accq(v5, a); accq(v6, a); accq(v7, a);
    }
    float inv = 1.0f / fmaxf((float)d, 1.0f);
    float4* op = reinterpret_cast<float4*>(mean2 + (size_t)node * 16 + f * 8);
    op[0] = make_float4(a[0] * inv, a[1] * inv, a[2] * inv, a[3] * inv);
    op[1] = make_float4(a[4] * inv, a[5] * inv, a[6] * inv, a[7] * inv);
}

// layer 3: 3 lanes/node over stride-24B fp8 table; self stride 24; out stride 21
__global__ void k_agg_l3(const unsigned char* __restrict__ y3q, const int* __restrict__ rs,
                         const int* __restrict__ deg, const int* __restrict__ perm,
                         const float* __restrict__ self24, float* __restrict__ outp,
                         int n_nodes) {
    int t = blockIdx.x * blockDim.x + threadIdx.x;
    int node = t / 3;
    int f = t - node * 3;
    if (node >= n_nodes) return;
    const uint2* yq = reinterpret_cast<const uint2*>(y3q);
    int beg = rs[node];
    int d = deg[node];
    int pend = beg + ((d + 7) & ~7);
    float a[8];
#pragma unroll
    for (int j = 0; j < 8; ++j) a[j] = 0.f;
    for (int e = beg; e < pend; e += 8) {
        const int4* pp = reinterpret_cast<const int4*>(perm + e);
        int4 p0 = pp[0];
        int4 p1 = pp[1];
        uint2 v0 = yq[(size_t)p0.x * 3 + f];
        uint2 v1 = yq[(size_t)p0.y * 3 + f];
        uint2 v2 = yq[(size_t)p0.z * 3 + f];
        uint2 v3 = yq[(size_t)p0.w * 3 + f];
        uint2 v4 = yq[(size_t)p1.x * 3 + f];
        uint2 v5 = yq[(size_t)p1.y * 3 + f];
        uint2 v6 = yq[(size_t)p1.z * 3 + f];
        uint2 v7 = yq[(size_t)p1.w * 3 + f];
        accq(v0, a); accq(v1, a); accq(v2, a); accq(v3, a);
        accq(v4, a); accq(v5, a); accq(v6, a); accq(v7, a);
    }
    float inv = 1.0f / fmaxf((float)d, 1.0f);
    int c0 = f * 8;
    const float4* sp = reinterpret_cast<const float4*>(self24 + (size_t)node * 24 + c0);
    float4 s0 = sp[0], s1 = sp[1];
    float r[8];
    r[0] = a[0] * inv + s0.x; r[1] = a[1] * inv + s0.y;
    r[2] = a[2] * inv + s0.z; r[3] = a[3] * inv + s0.w;
    r[4] = a[4] * inv + s1.x; r[5] = a[5] * inv + s1.y;
    r[6] = a[6] * inv + s1.z; r[7] = a[7] * inv + s1.w;
    float* op = outp + (size_t)node * 21;
    int nlim = 21 - c0;                 // 21, 13, or 5
#pragma unroll
    for (int j = 0; j < 8; ++j)
        if (j < nlim) op[c0 + j] = r[j];
}

// ---------------- pooling + classifier ----------------

__device__ __forceinline__ int lowerb(const int* a, int n, int key) {
    int lo = 0, hi = n;
    while (lo < hi) { int mid = (lo + hi) >> 1; if (a[mid] < key) lo = mid + 1; else hi = mid; }
    return lo;
}

__global__ void k_pool(const float* __restrict__ h2, const int* __restrict__ batch,
                       float* __restrict__ gsum, float* __restrict__ gcnt, int n) {
    int g = blockIdx.x / POOL_SLICES;
    int slice = blockIdx.x - g * POOL_SLICES;
    __shared__ int sbeg, send;
    if (threadIdx.x == 0) { sbeg = lowerb(batch, n, g); send = lowerb(batch, n, g + 1); }
    __syncthreads();
    int beg = sbeg, end = send;
    int f = threadIdx.x & 31;
    int r = threadIdx.x >> 5;   // 8 row-groups
    float acc = 0.f;
    for (int i = beg + slice * 8 + r; i < end; i += POOL_SLICES * 8)
        acc += h2[(size_t)i * 32 + f];
    __shared__ float red[256];
    red[threadIdx.x] = acc;
    __syncthreads();
    if (r == 0) {
        float s = 0.f;
#pragma unroll
        for (int q = 0; q < 8; ++q) s += red[q * 32 + f];
        atomicAdd(&gsum[g * 32 + f], s);
    }
    if (slice == 0 && threadIdx.x == 0) gcnt[g] = (float)(end - beg);
}

__global__ void k_cls(const float* __restrict__ gsum, const float* __restrict__ gcnt,
                      const float* __restrict__ Wc, const float* __restrict__ bc,
                      float* __restrict__ outp) {
    int t = threadIdx.x;
    if (t >= N_GRAPHS * 10) return;
    int g = t / 10, c = t - g * 10;
    float cv = fmaxf(gcnt[g], 1.f);
    float acc = bc[c];
#pragma unroll
    for (int k = 0; k < 32; ++k) acc += (gsum[g * 32 + k] / cv) * Wc[k * 10 + c];
    outp[g * 10 + c] = acc;
}

// ---------------- launch ----------------

extern "C" void kernel_launch(void* const* d_in, const int* in_sizes, int n_in,
                              void* d_out, int out_size, void* d_ws, size_t ws_size,
                              hipStream_t stream) {
    const float* x    = (const float*)d_in[0];
    const int*   ei   = (const int*)d_in[1];
    const int*   batch= (const int*)d_in[2];
    const float* W1l  = (const float*)d_in[3];
    const float* b1   = (const float*)d_in[4];
    const float* W1r  = (const float*)d_in[5];
    const float* W2l  = (const float*)d_in[6];
    const float* b2   = (const float*)d_in[7];
    const float* W2r  = (const float*)d_in[8];
    const float* W3l  = (const float*)d_in[9];
    const float* b3   = (const float*)d_in[10];
    const float* W3r  = (const float*)d_in[11];
    const float* Wc   = (const float*)d_in[12];
    const float* bc   = (const float*)d_in[13];
    float* out = (float*)d_out;

    char* ws = (char*)d_ws;
    size_t off = 0;
    auto alloc = [&](size_t bytes) { size_t o = off; off += (bytes + 255) & ~(size_t)255; return o; };

    int*    rs    = (int*)(ws + alloc((size_t)N_NODES * 4));
    int*    deg   = (int*)(ws + alloc((size_t)N_NODES * 4));
    int*    perm  = (int*)(ws + alloc((size_t)(N_EDGES + (size_t)NBUCK * PADB + 64) * 4));
    int*    gh    = (int*)(ws + alloc((size_t)NBUCK * NBLK * 4));
    int*    btotal= (int*)(ws + alloc(256 * 4));
    int*    bstart= (int*)(ws + alloc(260 * 4));
    uint2*  y1q   = (uint2*)(ws + alloc((size_t)(N_NODES + 1) * 16));      // fp8 [N+1][16]
    float*  s1    = (float*)(ws + alloc((size_t)N_NODES * 16 * 4));
    __half* h     = (__half*)(ws + alloc((size_t)N_NODES * 16 * 2));       // fp16 self copy
    uint2*  hq    = (uint2*)(ws + alloc((size_t)(N_NODES + 1) * 16));      // fp8 [N+1][16]
    float*  mean2 = (float*)(ws + alloc((size_t)N_NODES * 16 * 4));
    float*  h2    = (float*)(ws + alloc((size_t)N_NODES * 32 * 4));
    unsigned char* y3q = (unsigned char*)(ws + alloc((size_t)(N_NODES + 1) * 24)); // fp8 stride24
    float*  s3    = (float*)(ws + alloc((size_t)N_NODES * 24 * 4));
    float*  gsum  = (float*)(ws + alloc((size_t)N_GRAPHS * 32 * 4));
    float*  gcnt  = (float*)(ws + alloc((size_t)N_GRAPHS * 4));

    // tmp (12.8 MB) aliases h2 (12.8 MB): tmp dead before k_t2 writes h2
    unsigned* tmp = (unsigned*)h2;

    const int* src = ei;
    const int* dst = ei + N_EDGES;

    int nb  = (N_NODES + 255) / 256;                 // 391
    int g2  = (N_NODES * 2 + 255) / 256;             // 782
    int g3  = (N_NODES * 3 + 255) / 256;             // 1172

    // zero pad rows (gather row N_NODES) + gsum
    k_zero<<<1, 256, 0, stream>>>(y1q + (size_t)N_NODES * 2, hq + (size_t)N_NODES * 2,
                                  y3q + (size_t)N_NODES * 24, gsum);

    // CSR build (bucketed 2-pass counting sort, 8-padded per-node segments)
    kp1_hist   <<<NBLK, 256, 0, stream>>>(dst, gh, N_EDGES);
    kp1_scanA  <<<NBUCK, 256, 0, stream>>>(gh, btotal);
    kp1_scanB  <<<1, 256, 0, stream>>>(btotal, bstart);
    kp1_scatter<<<NBLK, 256, 0, stream>>>(src, dst, gh, bstart, tmp, N_EDGES);
    kp2        <<<NBUCK, 1024, 0, stream>>>(tmp, bstart, rs, deg, perm);

    // layer 1: transform-first (64->16); fp8-table aggregate (+self +relu) -> h fp16 + hq fp8
    k_t1<<<nb, 256, 0, stream>>>(x, W1l, W1r, b1, y1q, s1, N_NODES);
    k_agg_l1<<<g2, 256, 0, stream>>>(y1q, rs, deg, perm, s1, h, hq, N_NODES);

    // layer 2: fp8-table aggregate-first -> mean2 (f32), then 16->32
    k_agg_l2<<<g2, 256, 0, stream>>>(hq, rs, deg, perm, mean2, N_NODES);
    k_t2<<<nb, 256, 0, stream>>>(mean2, h, W2l, W2r, b2, h2, N_NODES);

    // layer 3: transform-first on relu(h2) (32->21); fp8-table aggregate, +self
    k_t3<<<nb, 256, 0, stream>>>(h2, W3l, W3r, b3, y3q, s3, N_NODES);
    k_agg_l3<<<g3, 256, 0, stream>>>(y3q, rs, deg, perm, s3, out + N_GRAPHS * 10, N_NODES);

    // pooling over h2 (pre-relu) + classifier
    k_pool<<<N_GRAPHS * POOL_SLICES, 256, 0, stream>>>(h2, batch, gsum, gcnt, N_NODES);
    k_cls<<<1, 640, 0, stream>>>(gsum, gcnt, Wc, bc, out);
}

// Round 16
// 203.015 us; speedup vs baseline: 1.4446x; 1.0586x over previous
//
#include <hip/hip_runtime.h>
#include <hip/hip_fp16.h>
#include <cstdint>
#include <cstddef>

#define N_NODES  100000
#define N_EDGES  3200000
#define N_GRAPHS 64

#define BQBITS   9
#define BQ       512                      // nodes per bucket
#define NBUCK    196                      // ceil(100000/512)
#define TILE     4096                     // edges per pass-1 block
#define NBLK     782                      // ceil(3200000/4096)
#define PADB     4608                     // per-bucket padding slack

typedef float vf2 __attribute__((ext_vector_type(2)));

// ---------------- CSR build: bucketed 2-pass counting sort ----------------

__global__ void kp1_hist(const int* __restrict__ dst, int* __restrict__ gh, int ne) {
    __shared__ int h[NBUCK];
    for (int i = threadIdx.x; i < NBUCK; i += 256) h[i] = 0;
    __syncthreads();
    int base = blockIdx.x * TILE;
    for (int i = threadIdx.x; i < TILE; i += 256) {
        int e = base + i;
        if (e < ne) atomicAdd(&h[dst[e] >> BQBITS], 1);
    }
    __syncthreads();
    for (int i = threadIdx.x; i < NBUCK; i += 256) gh[i * NBLK + blockIdx.x] = h[i];
}

__global__ void kp1_scanA(int* __restrict__ gh, int* __restrict__ btotal) {
    int q = blockIdx.x;
    __shared__ int ts[256];
    int v[4];
    int tsum = 0;
#pragma unroll
    for (int u = 0; u < 4; ++u) {
        int idx = threadIdx.x * 4 + u;
        v[u] = (idx < NBLK) ? gh[q * NBLK + idx] : 0;
        tsum += v[u];
    }
    ts[threadIdx.x] = tsum;
    __syncthreads();
    for (int off = 1; off < 256; off <<= 1) {
        int t = (threadIdx.x >= off) ? ts[threadIdx.x - off] : 0;
        __syncthreads();
        ts[threadIdx.x] += t;
        __syncthreads();
    }
    int run = ts[threadIdx.x] - tsum;
#pragma unroll
    for (int u = 0; u < 4; ++u) {
        int idx = threadIdx.x * 4 + u;
        if (idx < NBLK) gh[q * NBLK + idx] = run;
        run += v[u];
    }
    if (threadIdx.x == 255) btotal[q] = ts[255];
}

// scanB + pad-row zeroing + gsum zeroing (folded k_zero)
__global__ void kp1_scanB(const int* __restrict__ btotal, int* __restrict__ bstart,
                          uint2* __restrict__ y1qz, uint2* __restrict__ hqz,
                          unsigned char* __restrict__ y3qz, float* __restrict__ gsum) {
    __shared__ int s[256];
    int v = (threadIdx.x < NBUCK) ? btotal[threadIdx.x] : 0;
    s[threadIdx.x] = v;
    __syncthreads();
    for (int off = 1; off < 256; off <<= 1) {
        int t = (threadIdx.x >= off) ? s[threadIdx.x - off] : 0;
        __syncthreads();
        s[threadIdx.x] += t;
        __syncthreads();
    }
    if (threadIdx.x < NBUCK) bstart[threadIdx.x] = s[threadIdx.x] - v;
    if (threadIdx.x == 0) bstart[NBUCK] = N_EDGES;
    int t = threadIdx.x;
    if (t < 2) { y1qz[t] = make_uint2(0, 0); hqz[t] = make_uint2(0, 0); }
    if (t < 24) y3qz[t] = 0;
    for (int i = t; i < N_GRAPHS * 32; i += 256) gsum[i] = 0.f;
}

// block-local counting sort -> bucket-runs in LDS -> coalesced run copy to tmp
__global__ __launch_bounds__(256) void kp1_scatter(
        const int* __restrict__ src, const int* __restrict__ dst,
        const int* __restrict__ gh, const int* __restrict__ bstart,
        unsigned* __restrict__ tmp, int ne) {
    __shared__ unsigned sed[TILE];        // 16 KB
    __shared__ int lcnt[NBUCK];
    __shared__ int lofs[NBUCK + 1];
    __shared__ int fill[NBUCK];
    __shared__ int delta[NBUCK];
    __shared__ int ts[256];
    for (int i = threadIdx.x; i < NBUCK; i += 256) { lcnt[i] = 0; fill[i] = 0; }
    __syncthreads();
    int base = blockIdx.x * TILE;
    int nh = ne - base; if (nh > TILE) nh = TILE;
    int myq[16]; unsigned myw[16];
#pragma unroll
    for (int u = 0; u < 16; ++u) {
        int i = u * 256 + threadIdx.x;
        myq[u] = -1;
        if (i < nh) {
            int d = dst[base + i], s = src[base + i];
            int q = d >> BQBITS;
            myq[u] = q;
            myw[u] = ((unsigned)(d & (BQ - 1)) << 17) | (unsigned)s;
            atomicAdd(&lcnt[q], 1);
        }
    }
    __syncthreads();
    int v = (threadIdx.x < NBUCK) ? lcnt[threadIdx.x] : 0;
    ts[threadIdx.x] = v;
    __syncthreads();
    for (int off = 1; off < 256; off <<= 1) {
        int t = (threadIdx.x >= off) ? ts[threadIdx.x - off] : 0;
        __syncthreads();
        ts[threadIdx.x] += t;
        __syncthreads();
    }
    if (threadIdx.x < NBUCK) {
        int start = ts[threadIdx.x] - v;
        lofs[threadIdx.x] = start;
        delta[threadIdx.x] = bstart[threadIdx.x] + gh[threadIdx.x * NBLK + blockIdx.x] - start;
    }
    if (threadIdx.x == NBUCK - 1) lofs[NBUCK] = ts[threadIdx.x];
    __syncthreads();
#pragma unroll
    for (int u = 0; u < 16; ++u) {
        if (myq[u] >= 0) {
            int r = atomicAdd(&fill[myq[u]], 1);
            sed[lofs[myq[u]] + r] = myw[u];
        }
    }
    __syncthreads();
    for (int p = threadIdx.x; p < nh; p += 256) {
        int lo = 0, hi = NBUCK;                 // run q = largest with lofs[q] <= p
        while (hi - lo > 1) { int mid = (lo + hi) >> 1; if (lofs[mid] <= p) lo = mid; else hi = mid; }
        tmp[p + delta[lo]] = sed[p];
    }
}

// one block per bucket: node counting sort -> rs/deg + 8-padded perm segments
__global__ void kp2(const unsigned* __restrict__ tmp, const int* __restrict__ bstart,
                    int* __restrict__ rs, int* __restrict__ deg, int* __restrict__ perm) {
    int q = blockIdx.x;
    int beg = bstart[q], end = bstart[q + 1];
    int m = end - beg;
    int pbase = ((beg + 7) & ~7) + q * PADB;
    __shared__ int cnt[BQ];
    __shared__ int lofs[BQ];
    __shared__ int fill[BQ];
    if (threadIdx.x < BQ) { cnt[threadIdx.x] = 0; fill[threadIdx.x] = 0; }
    __syncthreads();
    for (int p = threadIdx.x; p < m; p += 1024)
        atomicAdd(&cnt[tmp[beg + p] >> 17], 1);
    __syncthreads();
    int pc = 0;
    if (threadIdx.x < BQ) { pc = (cnt[threadIdx.x] + 7) & ~7; lofs[threadIdx.x] = pc; }
    __syncthreads();
    for (int off = 1; off < BQ; off <<= 1) {
        int t = 0;
        if (threadIdx.x < BQ && threadIdx.x >= off) t = lofs[threadIdx.x - off];
        __syncthreads();
        if (threadIdx.x < BQ) lofs[threadIdx.x] += t;   // inclusive over padded counts
        __syncthreads();
    }
    if (threadIdx.x < BQ) {
        int node = q * BQ + threadIdx.x;
        if (node < N_NODES) {
            int st = lofs[threadIdx.x] - pc;
            rs[node] = pbase + st;
            deg[node] = cnt[threadIdx.x];
            for (int i = cnt[threadIdx.x]; i < pc; ++i)
                perm[pbase + st + i] = N_NODES;          // pad -> zero row
        }
    }
    __syncthreads();
    for (int p = threadIdx.x; p < m; p += 1024) {
        unsigned w = tmp[beg + p];
        int dl = w >> 17;
        int s = w & 0x1FFFF;
        int r = atomicAdd(&fill[dl], 1);
        int st = lofs[dl] - ((cnt[dl] + 7) & ~7);
        perm[pbase + st + r] = s;
    }
}

// ---------------- fp8 helpers (HW packed converts) ----------------

__device__ __forceinline__ void accq(uint2 v, float* a) {
    vf2 f0 = __builtin_amdgcn_cvt_pk_f32_fp8((int)v.x, false);
    vf2 f1 = __builtin_amdgcn_cvt_pk_f32_fp8((int)v.x, true);
    vf2 f2 = __builtin_amdgcn_cvt_pk_f32_fp8((int)v.y, false);
    vf2 f3 = __builtin_amdgcn_cvt_pk_f32_fp8((int)v.y, true);
    a[0] += f0.x; a[1] += f0.y; a[2] += f1.x; a[3] += f1.y;
    a[4] += f2.x; a[5] += f2.y; a[6] += f3.x; a[7] += f3.y;
}

__device__ __forceinline__ uint2 pack8_fp8(const float* a) {
    int lo = __builtin_amdgcn_cvt_pk_fp8_f32(a[0], a[1], 0, false);
    lo     = __builtin_amdgcn_cvt_pk_fp8_f32(a[2], a[3], lo, true);
    int hi = __builtin_amdgcn_cvt_pk_fp8_f32(a[4], a[5], 0, false);
    hi     = __builtin_amdgcn_cvt_pk_fp8_f32(a[6], a[7], hi, true);
    uint2 o; o.x = (unsigned)lo; o.y = (unsigned)hi; return o;
}

// ---------------- transforms ----------------

// y1q(fp8,[N][16]) = x @ W1l ; s1(f32) = x @ W1r + b1      (64 -> 16)
__global__ void k_t1(const float* __restrict__ x, const float* __restrict__ W1l,
                     const float* __restrict__ W1r, const float* __restrict__ b1,
                     uint2* __restrict__ y1q, float* __restrict__ s1, int n) {
    __shared__ float wl[64 * 16], wr[64 * 16], bb[16];
    for (int i = threadIdx.x; i < 64 * 16; i += blockDim.x) { wl[i] = W1l[i]; wr[i] = W1r[i]; }
    if (threadIdx.x < 16) bb[threadIdx.x] = b1[threadIdx.x];
    __syncthreads();
    int node = blockIdx.x * blockDim.x + threadIdx.x;
    if (node >= n) return;
    const float4* xr = reinterpret_cast<const float4*>(x + (size_t)node * 64);
    float accl[16], accr[16];
#pragma unroll
    for (int j = 0; j < 16; ++j) { accl[j] = 0.f; accr[j] = 0.f; }
#pragma unroll
    for (int q = 0; q < 16; ++q) {
        float4 v = xr[q];
        float xs[4] = {v.x, v.y, v.z, v.w};
#pragma unroll
        for (int u = 0; u < 4; ++u) {
            int k = q * 4 + u;
            float xv = xs[u];
#pragma unroll
            for (int j = 0; j < 16; ++j) {
                accl[j] += xv * wl[k * 16 + j];
                accr[j] += xv * wr[k * 16 + j];
            }
        }
    }
    y1q[(size_t)node * 2 + 0] = pack8_fp8(accl);
    y1q[(size_t)node * 2 + 1] = pack8_fp8(accl + 8);
    float4* s4 = reinterpret_cast<float4*>(s1 + (size_t)node * 16);
#pragma unroll
    for (int q = 0; q < 4; ++q)
        s4[q] = make_float4(accr[q*4+0] + bb[q*4+0], accr[q*4+1] + bb[q*4+1],
                            accr[q*4+2] + bb[q*4+2], accr[q*4+3] + bb[q*4+3]);
}

// fused t2+t3+pool: h2 kept in registers; y3q/s3 written; gsum accumulated via
// per-block segmented LDS reduction (batch sorted)
__global__ __launch_bounds__(256) void k_t23(
        const float* __restrict__ mean2, const __half* __restrict__ h,
        const float* __restrict__ W2l, const float* __restrict__ W2r,
        const float* __restrict__ b2,
        const float* __restrict__ W3l, const float* __restrict__ W3r,
        const float* __restrict__ b3,
        const int* __restrict__ batch,
        unsigned char* __restrict__ y3q, float* __restrict__ s3,
        float* __restrict__ gsum, int n) {
    __shared__ float wl2[16 * 32], wr2[16 * 32], bb2[32];
    __shared__ float wl3[32 * 21], wr3[32 * 21], bb3[21];
    __shared__ float buf[256][33];
    __shared__ int sbatch[256];
    for (int i = threadIdx.x; i < 16 * 32; i += 256) { wl2[i] = W2l[i]; wr2[i] = W2r[i]; }
    for (int i = threadIdx.x; i < 32 * 21; i += 256) { wl3[i] = W3l[i]; wr3[i] = W3r[i]; }
    if (threadIdx.x < 32) bb2[threadIdx.x] = b2[threadIdx.x];
    if (threadIdx.x < 21) bb3[threadIdx.x] = b3[threadIdx.x];
    __syncthreads();
    int node = blockIdx.x * 256 + threadIdx.x;
    bool valid = node < n;
    int nodeC = valid ? node : (n - 1);

    float m[16], hh[16];
    {
        const float4* m4 = reinterpret_cast<const float4*>(mean2 + (size_t)nodeC * 16);
#pragma unroll
        for (int q = 0; q < 4; ++q) {
            float4 a = m4[q];
            m[q*4+0]=a.x; m[q*4+1]=a.y; m[q*4+2]=a.z; m[q*4+3]=a.w;
        }
        alignas(16) __half hv[16];
        const uint4* hp = reinterpret_cast<const uint4*>(h + (size_t)nodeC * 16);
        reinterpret_cast<uint4*>(hv)[0] = hp[0];
        reinterpret_cast<uint4*>(hv)[1] = hp[1];
#pragma unroll
        for (int k = 0; k < 16; ++k) hh[k] = __half2float(hv[k]);
    }
    float acc[32];
#pragma unroll
    for (int j = 0; j < 32; ++j) acc[j] = bb2[j];
#pragma unroll
    for (int k = 0; k < 16; ++k) {
#pragma unroll
        for (int j = 0; j < 32; ++j)
            acc[j] += m[k] * wl2[k * 32 + j] + hh[k] * wr2[k * 32 + j];
    }
    // stage pre-relu h2 row for pooling
#pragma unroll
    for (int j = 0; j < 32; ++j) buf[threadIdx.x][j] = valid ? acc[j] : 0.f;
    sbatch[threadIdx.x] = batch[nodeC];
    __syncthreads();

    // layer-3 transform
    float z[32];
#pragma unroll
    for (int j = 0; j < 32; ++j) z[j] = fmaxf(acc[j], 0.f);
    float a[24], c[21];
#pragma unroll
    for (int j = 0; j < 21; ++j) { a[j] = 0.f; c[j] = bb3[j]; }
    a[21] = 0.f; a[22] = 0.f; a[23] = 0.f;
#pragma unroll
    for (int k = 0; k < 32; ++k) {
#pragma unroll
        for (int j = 0; j < 21; ++j) {
            a[j] += z[k] * wl3[k * 21 + j];
            c[j] += z[k] * wr3[k * 21 + j];
        }
    }
    if (valid) {
        uint2* yp = reinterpret_cast<uint2*>(y3q + (size_t)node * 24);
        yp[0] = pack8_fp8(a);
        yp[1] = pack8_fp8(a + 8);
        yp[2] = pack8_fp8(a + 16);
        float* so = s3 + (size_t)node * 24;
#pragma unroll
        for (int j = 0; j < 21; ++j) so[j] = c[j];
        so[21] = 0.f; so[22] = 0.f; so[23] = 0.f;
    }

    // segmented pooling reduction: 32 threads walk columns
    if (threadIdx.x < 32) {
        int f = threadIdx.x;
        int cur = sbatch[0];
        float s = 0.f;
        for (int r = 0; r < 256; ++r) {
            int g = sbatch[r];
            if (g != cur) { atomicAdd(&gsum[cur * 32 + f], s); s = 0.f; cur = g; }
            s += buf[r][f];
        }
        atomicAdd(&gsum[cur * 32 + f], s);
    }
}

// ---- aggregation: fp8 tables, padded segments, int4 perm loads ----

// layer 1: 2 lanes/node, gathers y1q (uint2 = 8 fp8), +self +relu -> h fp16 + hq fp8
__global__ void k_agg_l1(const uint2* __restrict__ yq, const int* __restrict__ rs,
                         const int* __restrict__ deg, const int* __restrict__ perm,
                         const float* __restrict__ s1, __half* __restrict__ h,
                         uint2* __restrict__ hq, int n_nodes) {
    int t = blockIdx.x * blockDim.x + threadIdx.x;
    int node = t >> 1;
    int f = t & 1;
    if (node >= n_nodes) return;
    int beg = rs[node];
    int d = deg[node];
    int pend = beg + ((d + 7) & ~7);
    float a[8];
#pragma unroll
    for (int j = 0; j < 8; ++j) a[j] = 0.f;
    for (int e = beg; e < pend; e += 8) {
        const int4* pp = reinterpret_cast<const int4*>(perm + e);
        int4 p0 = pp[0];
        int4 p1 = pp[1];
        uint2 v0 = yq[(size_t)p0.x * 2 + f];
        uint2 v1 = yq[(size_t)p0.y * 2 + f];
        uint2 v2 = yq[(size_t)p0.z * 2 + f];
        uint2 v3 = yq[(size_t)p0.w * 2 + f];
        uint2 v4 = yq[(size_t)p1.x * 2 + f];
        uint2 v5 = yq[(size_t)p1.y * 2 + f];
        uint2 v6 = yq[(size_t)p1.z * 2 + f];
        uint2 v7 = yq[(size_t)p1.w * 2 + f];
        accq(v0, a); accq(v1, a); accq(v2, a); accq(v3, a);
        accq(v4, a); accq(v5, a); accq(v6, a); accq(v7, a);
    }
    float inv = 1.0f / fmaxf((float)d, 1.0f);
    const float4* sp = reinterpret_cast<const float4*>(s1 + (size_t)node * 16 + f * 8);
    float4 s0 = sp[0], s1v = sp[1];
    a[0] = fmaxf(a[0] * inv + s0.x, 0.f);
    a[1] = fmaxf(a[1] * inv + s0.y, 0.f);
    a[2] = fmaxf(a[2] * inv + s0.z, 0.f);
    a[3] = fmaxf(a[3] * inv + s0.w, 0.f);
    a[4] = fmaxf(a[4] * inv + s1v.x, 0.f);
    a[5] = fmaxf(a[5] * inv + s1v.y, 0.f);
    a[6] = fmaxf(a[6] * inv + s1v.z, 0.f);
    a[7] = fmaxf(a[7] * inv + s1v.w, 0.f);
    // fp16 copy for k_t23 self-path
    __half2 p0h = __floats2half2_rn(a[0], a[1]);
    __half2 p1h = __floats2half2_rn(a[2], a[3]);
    __half2 p2h = __floats2half2_rn(a[4], a[5]);
    __half2 p3h = __floats2half2_rn(a[6], a[7]);
    uint4 o;
    o.x = *reinterpret_cast<unsigned*>(&p0h);
    o.y = *reinterpret_cast<unsigned*>(&p1h);
    o.z = *reinterpret_cast<unsigned*>(&p2h);
    o.w = *reinterpret_cast<unsigned*>(&p3h);
    reinterpret_cast<uint4*>(h)[(size_t)node * 2 + f] = o;
    // fp8 gather table for layer 2
    hq[(size_t)node * 2 + f] = pack8_fp8(a);
}

// layer 2: 2 lanes/node, gathers hq -> mean2 f32
__global__ void k_agg_l2(const uint2* __restrict__ hq, const int* __restrict__ rs,
                         const int* __restrict__ deg, const int* __restrict__ perm,
                         float* __restrict__ mean2, int n_nodes) {
    int t = blockIdx.x * blockDim.x + threadIdx.x;
    int node = t >> 1;
    int f = t & 1;
    if (node >= n_nodes) return;
    int beg = rs[node];
    int d = deg[node];
    int pend = beg + ((d + 7) & ~7);
    float a[8];
#pragma unroll
    for (int j = 0; j < 8; ++j) a[j] = 0.f;
    for (int e = beg; e < pend; e += 8) {
        const int4* pp = reinterpret_cast<const int4*>(perm + e);
        int4 p0 = pp[0];
        int4 p1 = pp[1];
        uint2 v0 = hq[(size_t)p0.x * 2 + f];
        uint2 v1 = hq[(size_t)p0.y * 2 + f];
        uint2 v2 = hq[(size_t)p0.z * 2 + f];
        uint2 v3 = hq[(size_t)p0.w * 2 + f];
        uint2 v4 = hq[(size_t)p1.x * 2 + f];
        uint2 v5 = hq[(size_t)p1.y * 2 + f];
        uint2 v6 = hq[(size_t)p1.z * 2 + f];
        uint2 v7 = hq[(size_t)p1.w * 2 + f];
        accq(v0, a); accq(v1, a); accq(v2, a); accq(v3, a);
        accq(v4, a); accq(v5, a); accq(v6, a); accq(v7, a);
    }
    float inv = 1.0f / fmaxf((float)d, 1.0f);
    float4* op = reinterpret_cast<float4*>(mean2 + (size_t)node * 16 + f * 8);
    op[0] = make_float4(a[0] * inv, a[1] * inv, a[2] * inv, a[3] * inv);
    op[1] = make_float4(a[4] * inv, a[5] * inv, a[6] * inv, a[7] * inv);
}

// layer 3: 3 lanes/node over stride-24B fp8 table; self stride 24; out stride 21
__global__ void k_agg_l3(const unsigned char* __restrict__ y3q, const int* __restrict__ rs,
                         const int* __restrict__ deg, const int* __restrict__ perm,
                         const float* __restrict__ self24, float* __restrict__ outp,
                         int n_nodes) {
    int t = blockIdx.x * blockDim.x + threadIdx.x;
    int node = t / 3;
    int f = t - node * 3;
    if (node >= n_nodes) return;
    const uint2* yq = reinterpret_cast<const uint2*>(y3q);
    int beg = rs[node];
    int d = deg[node];
    int pend = beg + ((d + 7) & ~7);
    float a[8];
#pragma unroll
    for (int j = 0; j < 8; ++j) a[j] = 0.f;
    for (int e = beg; e < pend; e += 8) {
        const int4* pp = reinterpret_cast<const int4*>(perm + e);
        int4 p0 = pp[0];
        int4 p1 = pp[1];
        uint2 v0 = yq[(size_t)p0.x * 3 + f];
        uint2 v1 = yq[(size_t)p0.y * 3 + f];
        uint2 v2 = yq[(size_t)p0.z * 3 + f];
        uint2 v3 = yq[(size_t)p0.w * 3 + f];
        uint2 v4 = yq[(size_t)p1.x * 3 + f];
        uint2 v5 = yq[(size_t)p1.y * 3 + f];
        uint2 v6 = yq[(size_t)p1.z * 3 + f];
        uint2 v7 = yq[(size_t)p1.w * 3 + f];
        accq(v0, a); accq(v1, a); accq(v2, a); accq(v3, a);
        accq(v4, a); accq(v5, a); accq(v6, a); accq(v7, a);
    }
    float inv = 1.0f / fmaxf((float)d, 1.0f);
    int c0 = f * 8;
    const float4* sp = reinterpret_cast<const float4*>(self24 + (size_t)node * 24 + c0);
    float4 s0 = sp[0], s1 = sp[1];
    float r[8];
    r[0] = a[0] * inv + s0.x; r[1] = a[1] * inv + s0.y;
    r[2] = a[2] * inv + s0.z; r[3] = a[3] * inv + s0.w;
    r[4] = a[4] * inv + s1.x; r[5] = a[5] * inv + s1.y;
    r[6] = a[6] * inv + s1.z; r[7] = a[7] * inv + s1.w;
    float* op = outp + (size_t)node * 21;
    int nlim = 21 - c0;                 // 21, 13, or 5
#pragma unroll
    for (int j = 0; j < 8; ++j)
        if (j < nlim) op[c0 + j] = r[j];
}

// ---------------- classifier (computes gcnt via binary search) ----------------

__device__ __forceinline__ int lowerb(const int* a, int n, int key) {
    int lo = 0, hi = n;
    while (lo < hi) { int mid = (lo + hi) >> 1; if (a[mid] < key) lo = mid + 1; else hi = mid; }
    return lo;
}

__global__ void k_cls(const float* __restrict__ gsum, const int* __restrict__ batch,
                      const float* __restrict__ Wc, const float* __restrict__ bc,
                      float* __restrict__ outp) {
    int t = threadIdx.x;
    if (t >= N_GRAPHS * 10) return;
    int g = t / 10, c = t - g * 10;
    int beg = lowerb(batch, N_NODES, g);
    int end = lowerb(batch, N_NODES, g + 1);
    float cv = fmaxf((float)(end - beg), 1.f);
    float acc = bc[c];
#pragma unroll
    for (int k = 0; k < 32; ++k) acc += (gsum[g * 32 + k] / cv) * Wc[k * 10 + c];
    outp[g * 10 + c] = acc;
}

// ---------------- launch ----------------

extern "C" void kernel_launch(void* const* d_in, const int* in_sizes, int n_in,
                              void* d_out, int out_size, void* d_ws, size_t ws_size,
                              hipStream_t stream) {
    const float* x    = (const float*)d_in[0];
    const int*   ei   = (const int*)d_in[1];
    const int*   batch= (const int*)d_in[2];
    const float* W1l  = (const float*)d_in[3];
    const float* b1   = (const float*)d_in[4];
    const float* W1r  = (const float*)d_in[5];
    const float* W2l  = (const float*)d_in[6];
    const float* b2   = (const float*)d_in[7];
    const float* W2r  = (const float*)d_in[8];
    const float* W3l  = (const float*)d_in[9];
    const float* b3   = (const float*)d_in[10];
    const float* W3r  = (const float*)d_in[11];
    const float* Wc   = (const float*)d_in[12];
    const float* bc   = (const float*)d_in[13];
    float* out = (float*)d_out;

    char* ws = (char*)d_ws;
    size_t off = 0;
    auto alloc = [&](size_t bytes) { size_t o = off; off += (bytes + 255) & ~(size_t)255; return o; };

    int*    rs    = (int*)(ws + alloc((size_t)N_NODES * 4));
    int*    deg   = (int*)(ws + alloc((size_t)N_NODES * 4));
    int*    perm  = (int*)(ws + alloc((size_t)(N_EDGES + (size_t)NBUCK * PADB + 64) * 4));
    int*    gh    = (int*)(ws + alloc((size_t)NBUCK * NBLK * 4));
    int*    btotal= (int*)(ws + alloc(256 * 4));
    int*    bstart= (int*)(ws + alloc(260 * 4));
    unsigned* tmp = (unsigned*)(ws + alloc((size_t)N_EDGES * 4));
    uint2*  y1q   = (uint2*)(ws + alloc((size_t)(N_NODES + 1) * 16));      // fp8 [N+1][16]
    float*  s1    = (float*)(ws + alloc((size_t)N_NODES * 16 * 4));
    __half* h     = (__half*)(ws + alloc((size_t)N_NODES * 16 * 2));       // fp16 self copy
    uint2*  hq    = (uint2*)(ws + alloc((size_t)(N_NODES + 1) * 16));      // fp8 [N+1][16]
    float*  mean2 = (float*)(ws + alloc((size_t)N_NODES * 16 * 4));
    unsigned char* y3q = (unsigned char*)(ws + alloc((size_t)(N_NODES + 1) * 24)); // fp8 stride24
    float*  s3    = (float*)(ws + alloc((size_t)N_NODES * 24 * 4));
    float*  gsum  = (float*)(ws + alloc((size_t)N_GRAPHS * 32 * 4));

    const int* src = ei;
    const int* dst = ei + N_EDGES;

    int nb  = (N_NODES + 255) / 256;                 // 391
    int g2  = (N_NODES * 2 + 255) / 256;             // 782
    int g3  = (N_NODES * 3 + 255) / 256;             // 1172

    // CSR build (bucketed 2-pass counting sort, 8-padded per-node segments);
    // scanB also zeroes pad rows + gsum
    kp1_hist   <<<NBLK, 256, 0, stream>>>(dst, gh, N_EDGES);
    kp1_scanA  <<<NBUCK, 256, 0, stream>>>(gh, btotal);
    kp1_scanB  <<<1, 256, 0, stream>>>(btotal, bstart,
                                       y1q + (size_t)N_NODES * 2, hq + (size_t)N_NODES * 2,
                                       y3q + (size_t)N_NODES * 24, gsum);
    kp1_scatter<<<NBLK, 256, 0, stream>>>(src, dst, gh, bstart, tmp, N_EDGES);
    kp2        <<<NBUCK, 1024, 0, stream>>>(tmp, bstart, rs, deg, perm);

    // layer 1: transform-first (64->16); fp8-table aggregate (+self +relu) -> h fp16 + hq fp8
    k_t1<<<nb, 256, 0, stream>>>(x, W1l, W1r, b1, y1q, s1, N_NODES);
    k_agg_l1<<<g2, 256, 0, stream>>>(y1q, rs, deg, perm, s1, h, hq, N_NODES);

    // layer 2: fp8-table aggregate-first -> mean2 (f32)
    k_agg_l2<<<g2, 256, 0, stream>>>(hq, rs, deg, perm, mean2, N_NODES);

    // fused t2+t3+pool: h2 stays in registers; emits y3q, s3, gsum
    k_t23<<<nb, 256, 0, stream>>>(mean2, h, W2l, W2r, b2, W3l, W3r, b3,
                                  batch, y3q, s3, gsum, N_NODES);

    // layer 3: fp8-table aggregate, +self -> color output
    k_agg_l3<<<g3, 256, 0, stream>>>(y3q, rs, deg, perm, s3, out + N_GRAPHS * 10, N_NODES);

    // classifier (computes per-graph counts via binary search)
    k_cls<<<1, 640, 0, stream>>>(gsum, batch, Wc, bc, out);
}

// Round 17
// 195.989 us; speedup vs baseline: 1.4964x; 1.0358x over previous
//
#include <hip/hip_runtime.h>
#include <hip/hip_fp16.h>
#include <cstdint>
#include <cstddef>

#define N_NODES  100000
#define N_EDGES  3200000
#define N_GRAPHS 64

#define BQBITS   9
#define BQ       512                      // nodes per bucket
#define NBUCK    196                      // ceil(100000/512)
#define TILE     4096                     // edges per pass-1 block
#define NBLK     782                      // ceil(3200000/4096)
#define PADB     4608                     // per-bucket padding slack

typedef float vf2 __attribute__((ext_vector_type(2)));

// ---------------- CSR build: bucketed 2-pass counting sort ----------------

// hist (int4 reads) + block-0 zeroing of pad rows and gsum
__global__ void kp1_hist(const int4* __restrict__ dst4, int* __restrict__ gh, int ne4,
                         uint2* __restrict__ y1qz, uint2* __restrict__ hqz,
                         unsigned char* __restrict__ y3qz, float* __restrict__ gsum) {
    __shared__ int h[NBUCK];
    for (int i = threadIdx.x; i < NBUCK; i += 256) h[i] = 0;
    __syncthreads();
    int base4 = blockIdx.x * (TILE / 4);
#pragma unroll
    for (int u = 0; u < 4; ++u) {
        int i = base4 + u * 256 + threadIdx.x;
        if (i < ne4) {
            int4 d = dst4[i];
            atomicAdd(&h[d.x >> BQBITS], 1);
            atomicAdd(&h[d.y >> BQBITS], 1);
            atomicAdd(&h[d.z >> BQBITS], 1);
            atomicAdd(&h[d.w >> BQBITS], 1);
        }
    }
    __syncthreads();
    for (int i = threadIdx.x; i < NBUCK; i += 256) gh[i * NBLK + blockIdx.x] = h[i];
    if (blockIdx.x == 0) {
        int t = threadIdx.x;
        if (t < 2) { y1qz[t] = make_uint2(0, 0); hqz[t] = make_uint2(0, 0); }
        if (t < 24) y3qz[t] = 0;
        for (int i = t; i < N_GRAPHS * 32; i += 256) gsum[i] = 0.f;
    }
}

__global__ void kp1_scanA(int* __restrict__ gh, int* __restrict__ btotal) {
    int q = blockIdx.x;
    __shared__ int ts[256];
    int v[4];
    int tsum = 0;
#pragma unroll
    for (int u = 0; u < 4; ++u) {
        int idx = threadIdx.x * 4 + u;
        v[u] = (idx < NBLK) ? gh[q * NBLK + idx] : 0;
        tsum += v[u];
    }
    ts[threadIdx.x] = tsum;
    __syncthreads();
    for (int off = 1; off < 256; off <<= 1) {
        int t = (threadIdx.x >= off) ? ts[threadIdx.x - off] : 0;
        __syncthreads();
        ts[threadIdx.x] += t;
        __syncthreads();
    }
    int run = ts[threadIdx.x] - tsum;
#pragma unroll
    for (int u = 0; u < 4; ++u) {
        int idx = threadIdx.x * 4 + u;
        if (idx < NBLK) gh[q * NBLK + idx] = run;
        run += v[u];
    }
    if (threadIdx.x == 255) btotal[q] = ts[255];
}

// block-local counting sort (int4 reads) -> bucket-runs in LDS -> coalesced copy;
// bucket starts derived in-block from btotal
__global__ __launch_bounds__(256) void kp1_scatter(
        const int4* __restrict__ src4, const int4* __restrict__ dst4,
        const int* __restrict__ gh, const int* __restrict__ btotal,
        unsigned* __restrict__ tmp, int ne4) {
    __shared__ unsigned sed[TILE];        // 16 KB
    __shared__ int lcnt[NBUCK];
    __shared__ int lofs[NBUCK + 1];
    __shared__ int fill[NBUCK];
    __shared__ int delta[NBUCK];
    __shared__ int ts[256];
    __shared__ int bst[256];
    for (int i = threadIdx.x; i < NBUCK; i += 256) { lcnt[i] = 0; fill[i] = 0; }
    int bv = (threadIdx.x < NBUCK) ? btotal[threadIdx.x] : 0;
    bst[threadIdx.x] = bv;
    __syncthreads();
    for (int off = 1; off < 256; off <<= 1) {
        int t = (threadIdx.x >= off) ? bst[threadIdx.x - off] : 0;
        __syncthreads();
        bst[threadIdx.x] += t;
        __syncthreads();
    }
    bst[threadIdx.x] -= bv;               // exclusive bucket starts
    __syncthreads();

    int base4 = blockIdx.x * (TILE / 4);
    int myq[16]; unsigned myw[16];
#pragma unroll
    for (int u = 0; u < 4; ++u) {
        int i4 = base4 + u * 256 + threadIdx.x;
        bool ok = i4 < ne4;
        int4 d = ok ? dst4[i4] : make_int4(0, 0, 0, 0);
        int4 s = ok ? src4[i4] : make_int4(0, 0, 0, 0);
        int dd[4] = {d.x, d.y, d.z, d.w};
        int ss[4] = {s.x, s.y, s.z, s.w};
#pragma unroll
        for (int c = 0; c < 4; ++c) {
            int idx = u * 4 + c;
            myq[idx] = -1;
            if (ok) {
                int q = dd[c] >> BQBITS;
                myq[idx] = q;
                myw[idx] = ((unsigned)(dd[c] & (BQ - 1)) << 17) | (unsigned)ss[c];
                atomicAdd(&lcnt[q], 1);
            }
        }
    }
    __syncthreads();
    int v = (threadIdx.x < NBUCK) ? lcnt[threadIdx.x] : 0;
    ts[threadIdx.x] = v;
    __syncthreads();
    for (int off = 1; off < 256; off <<= 1) {
        int t = (threadIdx.x >= off) ? ts[threadIdx.x - off] : 0;
        __syncthreads();
        ts[threadIdx.x] += t;
        __syncthreads();
    }
    if (threadIdx.x < NBUCK) {
        int start = ts[threadIdx.x] - v;
        lofs[threadIdx.x] = start;
        delta[threadIdx.x] = bst[threadIdx.x] + gh[threadIdx.x * NBLK + blockIdx.x] - start;
    }
    if (threadIdx.x == NBUCK - 1) lofs[NBUCK] = ts[threadIdx.x];
    __syncthreads();
#pragma unroll
    for (int u = 0; u < 16; ++u) {
        if (myq[u] >= 0) {
            int r = atomicAdd(&fill[myq[u]], 1);
            sed[lofs[myq[u]] + r] = myw[u];
        }
    }
    __syncthreads();
    int nh = ne4 * 4 - base4 * 4; if (nh > TILE) nh = TILE;
    for (int p = threadIdx.x; p < nh; p += 256) {
        int lo = 0, hi = NBUCK;                 // run q = largest with lofs[q] <= p
        while (hi - lo > 1) { int mid = (lo + hi) >> 1; if (lofs[mid] <= p) lo = mid; else hi = mid; }
        tmp[p + delta[lo]] = sed[p];
    }
}

// one block per bucket: node counting sort -> rs/deg + 8-padded perm segments;
// bucket bounds derived in-block from btotal
__global__ void kp2(const unsigned* __restrict__ tmp, const int* __restrict__ btotal,
                    int* __restrict__ rs, int* __restrict__ deg, int* __restrict__ perm) {
    int q = blockIdx.x;
    __shared__ int bst[256];
    __shared__ int sBeg, sEnd;
    if (threadIdx.x < 256) {
        int bv = (threadIdx.x < NBUCK) ? btotal[threadIdx.x] : 0;
        bst[threadIdx.x] = bv;
    }
    __syncthreads();
    for (int off = 1; off < 256; off <<= 1) {
        int t = 0;
        if (threadIdx.x < 256 && threadIdx.x >= off) t = bst[threadIdx.x - off];
        __syncthreads();
        if (threadIdx.x < 256) bst[threadIdx.x] += t;   // inclusive
        __syncthreads();
    }
    if (threadIdx.x == 0) {
        sBeg = (q == 0) ? 0 : bst[q - 1];
        sEnd = bst[q];
    }
    __syncthreads();
    int beg = sBeg, end = sEnd;
    int m = end - beg;
    int pbase = ((beg + 7) & ~7) + q * PADB;
    __shared__ int cnt[BQ];
    __shared__ int lofs[BQ];
    __shared__ int fill[BQ];
    if (threadIdx.x < BQ) { cnt[threadIdx.x] = 0; fill[threadIdx.x] = 0; }
    __syncthreads();
    for (int p = threadIdx.x; p < m; p += 1024)
        atomicAdd(&cnt[tmp[beg + p] >> 17], 1);
    __syncthreads();
    int pc = 0;
    if (threadIdx.x < BQ) { pc = (cnt[threadIdx.x] + 7) & ~7; lofs[threadIdx.x] = pc; }
    __syncthreads();
    for (int off = 1; off < BQ; off <<= 1) {
        int t = 0;
        if (threadIdx.x < BQ && threadIdx.x >= off) t = lofs[threadIdx.x - off];
        __syncthreads();
        if (threadIdx.x < BQ) lofs[threadIdx.x] += t;   // inclusive over padded counts
        __syncthreads();
    }
    if (threadIdx.x < BQ) {
        int node = q * BQ + threadIdx.x;
        if (node < N_NODES) {
            int st = lofs[threadIdx.x] - pc;
            rs[node] = pbase + st;
            deg[node] = cnt[threadIdx.x];
            for (int i = cnt[threadIdx.x]; i < pc; ++i)
                perm[pbase + st + i] = N_NODES;          // pad -> zero row
        }
    }
    __syncthreads();
    for (int p = threadIdx.x; p < m; p += 1024) {
        unsigned w = tmp[beg + p];
        int dl = w >> 17;
        int s = w & 0x1FFFF;
        int r = atomicAdd(&fill[dl], 1);
        int st = lofs[dl] - ((cnt[dl] + 7) & ~7);
        perm[pbase + st + r] = s;
    }
}

// ---------------- fp8 helpers (HW packed converts) ----------------

__device__ __forceinline__ void accq(uint2 v, float* a) {
    vf2 f0 = __builtin_amdgcn_cvt_pk_f32_fp8((int)v.x, false);
    vf2 f1 = __builtin_amdgcn_cvt_pk_f32_fp8((int)v.x, true);
    vf2 f2 = __builtin_amdgcn_cvt_pk_f32_fp8((int)v.y, false);
    vf2 f3 = __builtin_amdgcn_cvt_pk_f32_fp8((int)v.y, true);
    a[0] += f0.x; a[1] += f0.y; a[2] += f1.x; a[3] += f1.y;
    a[4] += f2.x; a[5] += f2.y; a[6] += f3.x; a[7] += f3.y;
}

__device__ __forceinline__ uint2 pack8_fp8(const float* a) {
    int lo = __builtin_amdgcn_cvt_pk_fp8_f32(a[0], a[1], 0, false);
    lo     = __builtin_amdgcn_cvt_pk_fp8_f32(a[2], a[3], lo, true);
    int hi = __builtin_amdgcn_cvt_pk_fp8_f32(a[4], a[5], 0, false);
    hi     = __builtin_amdgcn_cvt_pk_fp8_f32(a[6], a[7], hi, true);
    uint2 o; o.x = (unsigned)lo; o.y = (unsigned)hi; return o;
}

// ---------------- transforms ----------------

// y1q(fp8,[N][16]) = x @ W1l ; s1(f32) = x @ W1r + b1      (64 -> 16)
__global__ void k_t1(const float* __restrict__ x, const float* __restrict__ W1l,
                     const float* __restrict__ W1r, const float* __restrict__ b1,
                     uint2* __restrict__ y1q, float* __restrict__ s1, int n) {
    __shared__ float wl[64 * 16], wr[64 * 16], bb[16];
    for (int i = threadIdx.x; i < 64 * 16; i += blockDim.x) { wl[i] = W1l[i]; wr[i] = W1r[i]; }
    if (threadIdx.x < 16) bb[threadIdx.x] = b1[threadIdx.x];
    __syncthreads();
    int node = blockIdx.x * blockDim.x + threadIdx.x;
    if (node >= n) return;
    const float4* xr = reinterpret_cast<const float4*>(x + (size_t)node * 64);
    float accl[16], accr[16];
#pragma unroll
    for (int j = 0; j < 16; ++j) { accl[j] = 0.f; accr[j] = 0.f; }
#pragma unroll
    for (int q = 0; q < 16; ++q) {
        float4 v = xr[q];
        float xs[4] = {v.x, v.y, v.z, v.w};
#pragma unroll
        for (int u = 0; u < 4; ++u) {
            int k = q * 4 + u;
            float xv = xs[u];
#pragma unroll
            for (int j = 0; j < 16; ++j) {
                accl[j] += xv * wl[k * 16 + j];
                accr[j] += xv * wr[k * 16 + j];
            }
        }
    }
    y1q[(size_t)node * 2 + 0] = pack8_fp8(accl);
    y1q[(size_t)node * 2 + 1] = pack8_fp8(accl + 8);
    float4* s4 = reinterpret_cast<float4*>(s1 + (size_t)node * 16);
#pragma unroll
    for (int q = 0; q < 4; ++q)
        s4[q] = make_float4(accr[q*4+0] + bb[q*4+0], accr[q*4+1] + bb[q*4+1],
                            accr[q*4+2] + bb[q*4+2], accr[q*4+3] + bb[q*4+3]);
}

// fused t2+t3+pool: h2 kept in registers; y3q/s3 written; gsum accumulated via
// per-block segmented LDS reduction (batch sorted)
__global__ __launch_bounds__(256) void k_t23(
        const float* __restrict__ mean2, const __half* __restrict__ h,
        const float* __restrict__ W2l, const float* __restrict__ W2r,
        const float* __restrict__ b2,
        const float* __restrict__ W3l, const float* __restrict__ W3r,
        const float* __restrict__ b3,
        const int* __restrict__ batch,
        unsigned char* __restrict__ y3q, float* __restrict__ s3,
        float* __restrict__ gsum, int n) {
    __shared__ float wl2[16 * 32], wr2[16 * 32], bb2[32];
    __shared__ float wl3[32 * 21], wr3[32 * 21], bb3[21];
    __shared__ float buf[256][33];
    __shared__ int sbatch[256];
    for (int i = threadIdx.x; i < 16 * 32; i += 256) { wl2[i] = W2l[i]; wr2[i] = W2r[i]; }
    for (int i = threadIdx.x; i < 32 * 21; i += 256) { wl3[i] = W3l[i]; wr3[i] = W3r[i]; }
    if (threadIdx.x < 32) bb2[threadIdx.x] = b2[threadIdx.x];
    if (threadIdx.x < 21) bb3[threadIdx.x] = b3[threadIdx.x];
    __syncthreads();
    int node = blockIdx.x * 256 + threadIdx.x;
    bool valid = node < n;
    int nodeC = valid ? node : (n - 1);

    float m[16], hh[16];
    {
        const float4* m4 = reinterpret_cast<const float4*>(mean2 + (size_t)nodeC * 16);
#pragma unroll
        for (int q = 0; q < 4; ++q) {
            float4 a = m4[q];
            m[q*4+0]=a.x; m[q*4+1]=a.y; m[q*4+2]=a.z; m[q*4+3]=a.w;
        }
        alignas(16) __half hv[16];
        const uint4* hp = reinterpret_cast<const uint4*>(h + (size_t)nodeC * 16);
        reinterpret_cast<uint4*>(hv)[0] = hp[0];
        reinterpret_cast<uint4*>(hv)[1] = hp[1];
#pragma unroll
        for (int k = 0; k < 16; ++k) hh[k] = __half2float(hv[k]);
    }
    float acc[32];
#pragma unroll
    for (int j = 0; j < 32; ++j) acc[j] = bb2[j];
#pragma unroll
    for (int k = 0; k < 16; ++k) {
#pragma unroll
        for (int j = 0; j < 32; ++j)
            acc[j] += m[k] * wl2[k * 32 + j] + hh[k] * wr2[k * 32 + j];
    }
    // stage pre-relu h2 row for pooling
#pragma unroll
    for (int j = 0; j < 32; ++j) buf[threadIdx.x][j] = valid ? acc[j] : 0.f;
    sbatch[threadIdx.x] = batch[nodeC];
    __syncthreads();

    // layer-3 transform
    float z[32];
#pragma unroll
    for (int j = 0; j < 32; ++j) z[j] = fmaxf(acc[j], 0.f);
    float a[24], c[21];
#pragma unroll
    for (int j = 0; j < 21; ++j) { a[j] = 0.f; c[j] = bb3[j]; }
    a[21] = 0.f; a[22] = 0.f; a[23] = 0.f;
#pragma unroll
    for (int k = 0; k < 32; ++k) {
#pragma unroll
        for (int j = 0; j < 21; ++j) {
            a[j] += z[k] * wl3[k * 21 + j];
            c[j] += z[k] * wr3[k * 21 + j];
        }
    }
    if (valid) {
        uint2* yp = reinterpret_cast<uint2*>(y3q + (size_t)node * 24);
        yp[0] = pack8_fp8(a);
        yp[1] = pack8_fp8(a + 8);
        yp[2] = pack8_fp8(a + 16);
        float* so = s3 + (size_t)node * 24;
#pragma unroll
        for (int j = 0; j < 21; ++j) so[j] = c[j];
        so[21] = 0.f; so[22] = 0.f; so[23] = 0.f;
    }

    // segmented pooling reduction: 32 threads walk columns
    if (threadIdx.x < 32) {
        int f = threadIdx.x;
        int cur = sbatch[0];
        float s = 0.f;
        for (int r = 0; r < 256; ++r) {
            int g = sbatch[r];
            if (g != cur) { atomicAdd(&gsum[cur * 32 + f], s); s = 0.f; cur = g; }
            s += buf[r][f];
        }
        atomicAdd(&gsum[cur * 32 + f], s);
    }
}

// ---- aggregation: fp8 tables, padded segments, int4 perm loads ----

// layer 1: 2 lanes/node, gathers y1q (uint2 = 8 fp8), +self +relu -> h fp16 + hq fp8
__global__ void k_agg_l1(const uint2* __restrict__ yq, const int* __restrict__ rs,
                         const int* __restrict__ deg, const int* __restrict__ perm,
                         const float* __restrict__ s1, __half* __restrict__ h,
                         uint2* __restrict__ hq, int n_nodes) {
    int t = blockIdx.x * blockDim.x + threadIdx.x;
    int node = t >> 1;
    int f = t & 1;
    if (node >= n_nodes) return;
    int beg = rs[node];
    int d = deg[node];
    int pend = beg + ((d + 7) & ~7);
    float a[8];
#pragma unroll
    for (int j = 0; j < 8; ++j) a[j] = 0.f;
    for (int e = beg; e < pend; e += 8) {
        const int4* pp = reinterpret_cast<const int4*>(perm + e);
        int4 p0 = pp[0];
        int4 p1 = pp[1];
        uint2 v0 = yq[(size_t)p0.x * 2 + f];
        uint2 v1 = yq[(size_t)p0.y * 2 + f];
        uint2 v2 = yq[(size_t)p0.z * 2 + f];
        uint2 v3 = yq[(size_t)p0.w * 2 + f];
        uint2 v4 = yq[(size_t)p1.x * 2 + f];
        uint2 v5 = yq[(size_t)p1.y * 2 + f];
        uint2 v6 = yq[(size_t)p1.z * 2 + f];
        uint2 v7 = yq[(size_t)p1.w * 2 + f];
        accq(v0, a); accq(v1, a); accq(v2, a); accq(v3, a);
        accq(v4, a); accq(v5, a); accq(v6, a); accq(v7, a);
    }
    float inv = 1.0f / fmaxf((float)d, 1.0f);
    const float4* sp = reinterpret_cast<const float4*>(s1 + (size_t)node * 16 + f * 8);
    float4 s0 = sp[0], s1v = sp[1];
    a[0] = fmaxf(a[0] * inv + s0.x, 0.f);
    a[1] = fmaxf(a[1] * inv + s0.y, 0.f);
    a[2] = fmaxf(a[2] * inv + s0.z, 0.f);
    a[3] = fmaxf(a[3] * inv + s0.w, 0.f);
    a[4] = fmaxf(a[4] * inv + s1v.x, 0.f);
    a[5] = fmaxf(a[5] * inv + s1v.y, 0.f);
    a[6] = fmaxf(a[6] * inv + s1v.z, 0.f);
    a[7] = fmaxf(a[7] * inv + s1v.w, 0.f);
    // fp16 copy for k_t23 self-path
    __half2 p0h = __floats2half2_rn(a[0], a[1]);
    __half2 p1h = __floats2half2_rn(a[2], a[3]);
    __half2 p2h = __floats2half2_rn(a[4], a[5]);
    __half2 p3h = __floats2half2_rn(a[6], a[7]);
    uint4 o;
    o.x = *reinterpret_cast<unsigned*>(&p0h);
    o.y = *reinterpret_cast<unsigned*>(&p1h);
    o.z = *reinterpret_cast<unsigned*>(&p2h);
    o.w = *reinterpret_cast<unsigned*>(&p3h);
    reinterpret_cast<uint4*>(h)[(size_t)node * 2 + f] = o;
    // fp8 gather table for layer 2
    hq[(size_t)node * 2 + f] = pack8_fp8(a);
}

// layer 2: 2 lanes/node, gathers hq -> mean2 f32
__global__ void k_agg_l2(const uint2* __restrict__ hq, const int* __restrict__ rs,
                         const int* __restrict__ deg, const int* __restrict__ perm,
                         float* __restrict__ mean2, int n_nodes) {
    int t = blockIdx.x * blockDim.x + threadIdx.x;
    int node = t >> 1;
    int f = t & 1;
    if (node >= n_nodes) return;
    int beg = rs[node];
    int d = deg[node];
    int pend = beg + ((d + 7) & ~7);
    float a[8];
#pragma unroll
    for (int j = 0; j < 8; ++j) a[j] = 0.f;
    for (int e = beg; e < pend; e += 8) {
        const int4* pp = reinterpret_cast<const int4*>(perm + e);
        int4 p0 = pp[0];
        int4 p1 = pp[1];
        uint2 v0 = hq[(size_t)p0.x * 2 + f];
        uint2 v1 = hq[(size_t)p0.y * 2 + f];
        uint2 v2 = hq[(size_t)p0.z * 2 + f];
        uint2 v3 = hq[(size_t)p0.w * 2 + f];
        uint2 v4 = hq[(size_t)p1.x * 2 + f];
        uint2 v5 = hq[(size_t)p1.y * 2 + f];
        uint2 v6 = hq[(size_t)p1.z * 2 + f];
        uint2 v7 = hq[(size_t)p1.w * 2 + f];
        accq(v0, a); accq(v1, a); accq(v2, a); accq(v3, a);
        accq(v4, a); accq(v5, a); accq(v6, a); accq(v7, a);
    }
    float inv = 1.0f / fmaxf((float)d, 1.0f);
    float4* op = reinterpret_cast<float4*>(mean2 + (size_t)node * 16 + f * 8);
    op[0] = make_float4(a[0] * inv, a[1] * inv, a[2] * inv, a[3] * inv);
    op[1] = make_float4(a[4] * inv, a[5] * inv, a[6] * inv, a[7] * inv);
}

// layer 3: 3 lanes/node over stride-24B fp8 table; self stride 24; out stride 21
__global__ void k_agg_l3(const unsigned char* __restrict__ y3q, const int* __restrict__ rs,
                         const int* __restrict__ deg, const int* __restrict__ perm,
                         const float* __restrict__ self24, float* __restrict__ outp,
                         int n_nodes) {
    int t = blockIdx.x * blockDim.x + threadIdx.x;
    int node = t / 3;
    int f = t - node * 3;
    if (node >= n_nodes) return;
    const uint2* yq = reinterpret_cast<const uint2*>(y3q);
    int beg = rs[node];
    int d = deg[node];
    int pend = beg + ((d + 7) & ~7);
    float a[8];
#pragma unroll
    for (int j = 0; j < 8; ++j) a[j] = 0.f;
    for (int e = beg; e < pend; e += 8) {
        const int4* pp = reinterpret_cast<const int4*>(perm + e);
        int4 p0 = pp[0];
        int4 p1 = pp[1];
        uint2 v0 = yq[(size_t)p0.x * 3 + f];
        uint2 v1 = yq[(size_t)p0.y * 3 + f];
        uint2 v2 = yq[(size_t)p0.z * 3 + f];
        uint2 v3 = yq[(size_t)p0.w * 3 + f];
        uint2 v4 = yq[(size_t)p1.x * 3 + f];
        uint2 v5 = yq[(size_t)p1.y * 3 + f];
        uint2 v6 = yq[(size_t)p1.z * 3 + f];
        uint2 v7 = yq[(size_t)p1.w * 3 + f];
        accq(v0, a); accq(v1, a); accq(v2, a); accq(v3, a);
        accq(v4, a); accq(v5, a); accq(v6, a); accq(v7, a);
    }
    float inv = 1.0f / fmaxf((float)d, 1.0f);
    int c0 = f * 8;
    const float4* sp = reinterpret_cast<const float4*>(self24 + (size_t)node * 24 + c0);
    float4 s0 = sp[0], s1 = sp[1];
    float r[8];
    r[0] = a[0] * inv + s0.x; r[1] = a[1] * inv + s0.y;
    r[2] = a[2] * inv + s0.z; r[3] = a[3] * inv + s0.w;
    r[4] = a[4] * inv + s1.x; r[5] = a[5] * inv + s1.y;
    r[6] = a[6] * inv + s1.z; r[7] = a[7] * inv + s1.w;
    float* op = outp + (size_t)node * 21;
    int nlim = 21 - c0;                 // 21, 13, or 5
#pragma unroll
    for (int j = 0; j < 8; ++j)
        if (j < nlim) op[c0 + j] = r[j];
}

// ---------------- classifier (computes gcnt via binary search) ----------------

__device__ __forceinline__ int lowerb(const int* a, int n, int key) {
    int lo = 0, hi = n;
    while (lo < hi) { int mid = (lo + hi) >> 1; if (a[mid] < key) lo = mid + 1; else hi = mid; }
    return lo;
}

__global__ void k_cls(const float* __restrict__ gsum, const int* __restrict__ batch,
                      const float* __restrict__ Wc, const float* __restrict__ bc,
                      float* __restrict__ outp) {
    int t = threadIdx.x;
    if (t >= N_GRAPHS * 10) return;
    int g = t / 10, c = t - g * 10;
    int beg = lowerb(batch, N_NODES, g);
    int end = lowerb(batch, N_NODES, g + 1);
    float cv = fmaxf((float)(end - beg), 1.f);
    float acc = bc[c];
#pragma unroll
    for (int k = 0; k < 32; ++k) acc += (gsum[g * 32 + k] / cv) * Wc[k * 10 + c];
    outp[g * 10 + c] = acc;
}

// ---------------- launch ----------------

extern "C" void kernel_launch(void* const* d_in, const int* in_sizes, int n_in,
                              void* d_out, int out_size, void* d_ws, size_t ws_size,
                              hipStream_t stream) {
    const float* x    = (const float*)d_in[0];
    const int*   ei   = (const int*)d_in[1];
    const int*   batch= (const int*)d_in[2];
    const float* W1l  = (const float*)d_in[3];
    const float* b1   = (const float*)d_in[4];
    const float* W1r  = (const float*)d_in[5];
    const float* W2l  = (const float*)d_in[6];
    const float* b2   = (const float*)d_in[7];
    const float* W2r  = (const float*)d_in[8];
    const float* W3l  = (const float*)d_in[9];
    const float* b3   = (const float*)d_in[10];
    const float* W3r  = (const float*)d_in[11];
    const float* Wc   = (const float*)d_in[12];
    const float* bc   = (const float*)d_in[13];
    float* out = (float*)d_out;

    char* ws = (char*)d_ws;
    size_t off = 0;
    auto alloc = [&](size_t bytes) { size_t o = off; off += (bytes + 255) & ~(size_t)255; return o; };

    int*    rs    = (int*)(ws + alloc((size_t)N_NODES * 4));
    int*    deg   = (int*)(ws + alloc((size_t)N_NODES * 4));
    int*    perm  = (int*)(ws + alloc((size_t)(N_EDGES + (size_t)NBUCK * PADB + 64) * 4));
    int*    gh    = (int*)(ws + alloc((size_t)NBUCK * NBLK * 4));
    int*    btotal= (int*)(ws + alloc(256 * 4));
    unsigned* tmp = (unsigned*)(ws + alloc((size_t)N_EDGES * 4));
    uint2*  y1q   = (uint2*)(ws + alloc((size_t)(N_NODES + 1) * 16));      // fp8 [N+1][16]
    float*  s1    = (float*)(ws + alloc((size_t)N_NODES * 16 * 4));
    __half* h     = (__half*)(ws + alloc((size_t)N_NODES * 16 * 2));       // fp16 self copy
    uint2*  hq    = (uint2*)(ws + alloc((size_t)(N_NODES + 1) * 16));      // fp8 [N+1][16]
    float*  mean2 = (float*)(ws + alloc((size_t)N_NODES * 16 * 4));
    unsigned char* y3q = (unsigned char*)(ws + alloc((size_t)(N_NODES + 1) * 24)); // fp8 stride24
    float*  s3    = (float*)(ws + alloc((size_t)N_NODES * 24 * 4));
    float*  gsum  = (float*)(ws + alloc((size_t)N_GRAPHS * 32 * 4));

    const int4* src4 = (const int4*)ei;
    const int4* dst4 = (const int4*)(ei + N_EDGES);
    const int ne4 = N_EDGES / 4;

    int nb  = (N_NODES + 255) / 256;                 // 391
    int g2  = (N_NODES * 2 + 255) / 256;             // 782
    int g3  = (N_NODES * 3 + 255) / 256;             // 1172

    // CSR build (bucketed 2-pass counting sort, 8-padded per-node segments);
    // hist block 0 zeroes pad rows + gsum; bucket starts derived in-block
    kp1_hist   <<<NBLK, 256, 0, stream>>>(dst4, gh, ne4,
                                          y1q + (size_t)N_NODES * 2, hq + (size_t)N_NODES * 2,
                                          y3q + (size_t)N_NODES * 24, gsum);
    kp1_scanA  <<<NBUCK, 256, 0, stream>>>(gh, btotal);
    kp1_scatter<<<NBLK, 256, 0, stream>>>(src4, dst4, gh, btotal, tmp, ne4);
    kp2        <<<NBUCK, 1024, 0, stream>>>(tmp, btotal, rs, deg, perm);

    // layer 1: transform-first (64->16); fp8-table aggregate (+self +relu) -> h fp16 + hq fp8
    k_t1<<<nb, 256, 0, stream>>>(x, W1l, W1r, b1, y1q, s1, N_NODES);
    k_agg_l1<<<g2, 256, 0, stream>>>(y1q, rs, deg, perm, s1, h, hq, N_NODES);

    // layer 2: fp8-table aggregate-first -> mean2 (f32)
    k_agg_l2<<<g2, 256, 0, stream>>>(hq, rs, deg, perm, mean2, N_NODES);

    // fused t2+t3+pool: h2 stays in registers; emits y3q, s3, gsum
    k_t23<<<nb, 256, 0, stream>>>(mean2, h, W2l, W2r, b2, W3l, W3r, b3,
                                  batch, y3q, s3, gsum, N_NODES);

    // layer 3: fp8-table aggregate, +self -> color output
    k_agg_l3<<<g3, 256, 0, stream>>>(y3q, rs, deg, perm, s3, out + N_GRAPHS * 10, N_NODES);

    // classifier (computes per-graph counts via binary search)
    k_cls<<<1, 640, 0, stream>>>(gsum, batch, Wc, bc, out);
}